// Round 2
// baseline (6356.198 us; speedup 1.0000x reference)
//
#include <hip/hip_runtime.h>
#include <math.h>

#define NV 24576
#define NC 98304
#define NE 294912
#define CMCHUNK 12288  // 8 chunks over NC

typedef unsigned short bf16;

static constexpr float INV_CQM = 1.0f / 12582912.0f;  // 1/(NC*128)

__device__ __forceinline__ float b2f(bf16 h) { return __uint_as_float(((unsigned)h) << 16); }
__device__ __forceinline__ bf16 f2b(float f) {
  unsigned u = __float_as_uint(f);
  u += 0x7fff + ((u >> 16) & 1);  // RNE
  return (bf16)(u >> 16);
}
__device__ __forceinline__ float dsigm(float x) { return 1.0f / (1.0f + expf(-x)); }
__device__ __forceinline__ float dsoftplus(float x) { return fmaxf(x, 0.0f) + log1pf(expf(-fabsf(x))); }
__device__ __forceinline__ float cvt_ld(float x) { return x; }
__device__ __forceinline__ float cvt_ld(bf16 x) { return b2f(x); }

// ---------------- precompute kernels ----------------

__global__ __launch_bounds__(256) void k_cptr(const int* __restrict__ ec, int* __restrict__ ptr) {
  int c = blockIdx.x * 256 + threadIdx.x;
  if (c > NC) return;
  int lo = 0, hi = NE;
  while (lo < hi) { int mid = (lo + hi) >> 1; if (ec[mid] < c) lo = mid + 1; else hi = mid; }
  ptr[c] = lo;
}

__global__ __launch_bounds__(256) void k_litcnt(const int* __restrict__ el, int* __restrict__ cnt) {
  int e = blockIdx.x * 256 + threadIdx.x;
  atomicAdd(&cnt[el[e]], 1);
}

__global__ __launch_bounds__(1024) void k_scan(int* __restrict__ cnt, int* __restrict__ ptr) {
  __shared__ int wsum[16];
  __shared__ int carry_s;
  int tid = threadIdx.x, lane = tid & 63, w = tid >> 6;
  if (tid == 0) carry_s = 0;
  __syncthreads();
  for (int base = 0; base < 2 * NV; base += 1024) {
    int x = cnt[base + tid];
    int v = x;
#pragma unroll
    for (int off = 1; off < 64; off <<= 1) {
      int y = __shfl_up(v, off, 64);
      if (lane >= off) v += y;
    }
    if (lane == 63) wsum[w] = v;
    __syncthreads();
    int carry = carry_s;
    int wpre = 0;
    for (int i = 0; i < w; ++i) wpre += wsum[i];
    int excl = carry + wpre + (v - x);
    ptr[base + tid] = excl;
    cnt[base + tid] = excl;
    __syncthreads();
    if (tid == 1023) carry_s = carry + wpre + v;
  }
  __syncthreads();
  if (tid == 0) ptr[2 * NV] = carry_s;
}

__global__ __launch_bounds__(256) void k_fillsort(const int* __restrict__ el, const int* __restrict__ ec,
                                                  int* __restrict__ cur, int* __restrict__ lclause) {
  int e = blockIdx.x * 256 + threadIdx.x;
  int pos = atomicAdd(&cur[el[e]], 1);
  lclause[pos] = ec[e];
}

__global__ __launch_bounds__(256) void k_degree(const int* __restrict__ lptr, float* __restrict__ dw,
                                                float* __restrict__ vdw) {
  int l = blockIdx.x * 256 + threadIdx.x;
  if (l < 2 * NV) dw[l] = rsqrtf(fmaxf((float)(lptr[l + 1] - lptr[l]), 1.0f));
  if (l < NV) {
    int d = (lptr[l + 1] - lptr[l]) + (lptr[l + NV + 1] - lptr[l + NV]);
    vdw[l] = 4.0f * rsqrtf(fmaxf((float)d, 1.0f));
  }
}

__global__ __launch_bounds__(256) void k_fill1(float* __restrict__ p) {
  p[blockIdx.x * 256 + threadIdx.x] = 1.0f;
}

// ---------------- GEMM (f32 accum, BM=64 BN=128 BK=16, 8x4 micro) ----------------

enum { L_PLAIN_F = 0, L_PLAIN_H, L_VN, L_CM, L_UG };

template <int KDIM, int LOADER>
__device__ __forceinline__ float loadA(const void* A0, const void* A1, const void* A2, const void* A3,
                                       int row, int k) {
  if constexpr (LOADER == L_PLAIN_F) {
    return ((const float*)A0)[(size_t)row * KDIM + k];
  } else if constexpr (LOADER == L_PLAIN_H) {
    return b2f(((const bf16*)A0)[(size_t)row * KDIM + k]);
  } else if constexpr (LOADER == L_VN) {  // [state(128) f32, noise(4) f32]
    if (k < 128) return ((const float*)A0)[(size_t)row * 128 + k];
    return ((const float*)A1)[(size_t)row * 4 + (k - 128)];
  } else if constexpr (LOADER == L_CM) {  // [clauses f32, 4*loss bf16, cg bf16]
    if (k < 128) return ((const float*)A0)[(size_t)row * 128 + k];
    if (k < 256) return 4.0f * b2f(((const bf16*)A1)[(size_t)row * 128 + (k - 128)]);
    return b2f(((const bf16*)A2)[(size_t)row * 128 + (k - 256)]);
  } else {  // L_UG: [vgrad f32, variables f32, vl_lo*dw, vl_hi*dw]
    if (k < 128) return ((const float*)A0)[(size_t)row * 128 + k];
    if (k < 256) return ((const float*)A1)[(size_t)row * 128 + (k - 128)];
    if (k < 384) return b2f(((const bf16*)A2)[(size_t)row * 128 + (k - 256)]) * ((const float*)A3)[row];
    return b2f(((const bf16*)A2)[(size_t)(row + NV) * 128 + (k - 384)]) * ((const float*)A3)[row + NV];
  }
}

// OUTB: bf16 output. DUAL: N=256 split at col 128 into out0/out1 (both ld=128).
template <int KDIM, bool RELU, int LOADER, bool OUTB, bool DUAL>
__global__ __launch_bounds__(256) void gemm_k(const void* A0, const void* A1, const void* A2, const void* A3,
                                              const float* __restrict__ W, const float* __restrict__ Bv,
                                              void* out0, void* out1, int ldW, int ldOut) {
  constexpr int BK = 16;
  __shared__ float a_s[BK][64];
  __shared__ float b_s[BK][128];
  const int bm = blockIdx.x * 64;
  const int bn = blockIdx.y * 128;
  const int tid = threadIdx.x;
  const int ty = tid >> 5;
  const int tx = tid & 31;
  const int am = tid >> 4;
  const int ak = tid & 15;
  const int bn0 = tid & 127;
  const int bk0 = tid >> 7;
  float acc[8][4] = {};
  for (int k0 = 0; k0 < KDIM; k0 += BK) {
#pragma unroll
    for (int p = 0; p < 4; ++p) {
      int k = k0 + ak;
      float v = 0.0f;
      if (KDIM % BK == 0 || k < KDIM) v = loadA<KDIM, LOADER>(A0, A1, A2, A3, bm + am + p * 16, k);
      a_s[ak][am + p * 16] = v;
    }
#pragma unroll
    for (int p = 0; p < 8; ++p) {
      int kk = bk0 + p * 2;
      int k = k0 + kk;
      b_s[kk][bn0] = (KDIM % BK == 0 || k < KDIM) ? W[(size_t)k * ldW + bn + bn0] : 0.0f;
    }
    __syncthreads();
#pragma unroll
    for (int kk = 0; kk < BK; ++kk) {
      const float4 a0 = *reinterpret_cast<const float4*>(&a_s[kk][ty * 8]);
      const float4 a1 = *reinterpret_cast<const float4*>(&a_s[kk][ty * 8 + 4]);
      const float4 b0 = *reinterpret_cast<const float4*>(&b_s[kk][tx * 4]);
      float av[8] = {a0.x, a0.y, a0.z, a0.w, a1.x, a1.y, a1.z, a1.w};
      float bv[4] = {b0.x, b0.y, b0.z, b0.w};
#pragma unroll
      for (int i = 0; i < 8; ++i)
#pragma unroll
        for (int j = 0; j < 4; ++j) acc[i][j] = fmaf(av[i], bv[j], acc[i][j]);
    }
    __syncthreads();
  }
  const int ng = bn + tx * 4;  // global output column (bias index)
  float4 bias = *reinterpret_cast<const float4*>(&Bv[ng]);
  void* outp;
  int ldo, nc;
  if constexpr (DUAL) {
    outp = blockIdx.y ? out1 : out0;
    ldo = 128;
    nc = tx * 4;
  } else {
    outp = out0;
    ldo = ldOut;
    nc = ng;
  }
#pragma unroll
  for (int i = 0; i < 8; ++i) {
    int row = bm + ty * 8 + i;
    float r[4] = {acc[i][0] + bias.x, acc[i][1] + bias.y, acc[i][2] + bias.z, acc[i][3] + bias.w};
    if (RELU) {
#pragma unroll
      for (int j = 0; j < 4; ++j) r[j] = fmaxf(r[j], 0.0f);
    }
    if constexpr (OUTB) {
      ushort4 pk;
      pk.x = f2b(r[0]); pk.y = f2b(r[1]); pk.z = f2b(r[2]); pk.w = f2b(r[3]);
      *reinterpret_cast<ushort4*>(&((bf16*)outp)[(size_t)row * ldo + nc]) = pk;
    } else {
      float4 fr = {r[0], r[1], r[2], r[3]};
      *reinterpret_cast<float4*>(&((float*)outp)[(size_t)row * ldo + nc]) = fr;
    }
  }
}

// ---------------- graph / elementwise kernels ----------------

__global__ __launch_bounds__(256) void k_loss(const int* __restrict__ edge_lit, const int* __restrict__ cptr,
                                              const float* __restrict__ vq, const bf16* __restrict__ cq,
                                              bf16* __restrict__ loss, bf16* __restrict__ cg) {
  int c = blockIdx.x * 2 + (threadIdx.x >> 7);
  int q = threadIdx.x & 127;
  int e0 = cptr[c], e1 = cptr[c + 1];
  float csum = 0.0f;
  for (int e = e0; e < e1; ++e) {
    int lit = edge_lit[e];
    float x = (lit < NV) ? vq[(size_t)lit * 128 + q] : -vq[(size_t)(lit - NV) * 128 + q];
    csum += dsoftplus(x);
  }
  float s = dsigm(b2f(cq[(size_t)c * 128 + q]));
  float L = expf(-csum) * s;
  loss[(size_t)c * 128 + q] = f2b(L);
  cg[(size_t)c * 128 + q] = f2b(L * (1.0f - s) * INV_CQM);
}

__global__ __launch_bounds__(256) void k_gather(const int* __restrict__ lptr, const int* __restrict__ lclause,
                                                const bf16* __restrict__ loss, const bf16* __restrict__ cd0,
                                                bf16* __restrict__ gl, bf16* __restrict__ vl) {
  int l = blockIdx.x * 2 + (threadIdx.x >> 7);
  int q = threadIdx.x & 127;
  int j0 = lptr[l], j1 = lptr[l + 1];
  float sg = 0.0f, sv = 0.0f;
  for (int j = j0; j < j1; ++j) {
    int c = lclause[j];
    sg += b2f(loss[(size_t)c * 128 + q]);
    sv += b2f(cd0[(size_t)c * 128 + q]);
  }
  gl[(size_t)l * 128 + q] = f2b(sg);
  vl[(size_t)l * 128 + q] = f2b(sv);
}

__global__ __launch_bounds__(256) void k_vgrad(const float* __restrict__ vq, const bf16* __restrict__ gl,
                                               const float* __restrict__ vdw, float* __restrict__ vgrad) {
  int i = blockIdx.x * 256 + threadIdx.x;
  int v = i >> 7;
  float x = vq[i];
  vgrad[i] = (dsigm(-x) * b2f(gl[i + NV * 128]) - dsigm(x) * b2f(gl[i])) * INV_CQM * vdw[v];
}

template <typename T>
__global__ __launch_bounds__(256) void k_pn_stats(const T* __restrict__ X, int R, float* __restrict__ stats) {
  int q = threadIdx.x & 127;
  int rg = threadIdx.x >> 7;
  float cs = 0.0f, ss = 0.0f;
  for (int r = blockIdx.x * 2 + rg; r < R; r += gridDim.x * 2) {
    float x = cvt_ld(X[(size_t)r * 128 + q]);
    cs += x;
    ss += x * x;
  }
  __shared__ float scs[256], sss[256];
  scs[threadIdx.x] = cs;
  sss[threadIdx.x] = ss;
  __syncthreads();
  if (threadIdx.x < 128) atomicAdd(&stats[q], scs[q] + scs[128 + q]);
  for (int off = 128; off; off >>= 1) {
    if (threadIdx.x < off) sss[threadIdx.x] += sss[threadIdx.x + off];
    __syncthreads();
  }
  if (threadIdx.x == 0) atomicAdd(&stats[128], sss[0]);
}

__global__ __launch_bounds__(128) void k_pn_final(float* __restrict__ stats, float R) {
  __shared__ float s[128];
  int q = threadIdx.x;
  float m = stats[q] / R;
  s[q] = m * m;
  __syncthreads();
  for (int off = 64; off; off >>= 1) {
    if (q < off) s[q] += s[q + off];
    __syncthreads();
  }
  if (q == 0) {
    float var = (stats[128] - R * s[0]) / (R * 128.0f);
    stats[129] = rsqrtf(fmaxf(var, 0.0f) + 1e-6f) * 0.25f;
  }
  stats[q] = m;
}

template <typename T>
__global__ __launch_bounds__(256) void k_pn_apply(const T* __restrict__ X, const float* __restrict__ stats,
                                                  float* __restrict__ state) {
  int i = blockIdx.x * 256 + threadIdx.x;
  int q = i & 127;
  float x = cvt_ld(X[i]);
  state[i] = (x - stats[q]) * stats[129] + 0.1f * state[i];
}

__global__ __launch_bounds__(256) void k_logits(const bf16* __restrict__ lh, const float* __restrict__ w1,
                                                const float* __restrict__ b1, float* __restrict__ outp, int t) {
  int wv = threadIdx.x >> 6, lane = threadIdx.x & 63;
  int c = blockIdx.x * 4 + wv;
  const bf16* row = lh + (size_t)c * 128;
  float v = b2f(row[lane]) * w1[lane] + b2f(row[64 + lane]) * w1[64 + lane];
#pragma unroll
  for (int off = 32; off; off >>= 1) v += __shfl_down(v, off, 64);
  if (lane == 0) {
    float lg = v + b1[0];
    outp[(size_t)t * NC + c] = 1.0f / (1.0f + expf(-lg));
    outp[(size_t)4 * NC + (size_t)t * NC + c] = dsoftplus(lg);
  }
}

// ---------------- host ----------------

extern "C" void kernel_launch(void* const* d_in, const int* in_sizes, int n_in,
                              void* d_out, int out_size, void* d_ws, size_t ws_size,
                              hipStream_t stream) {
  const int* edge_lit = (const int*)d_in[0];
  const int* edge_clause = (const int*)d_in[1];
  const float* noise_v = (const float*)d_in[2];
  const float* noise_c = (const float*)d_in[3];
  const float* vq_w0 = (const float*)d_in[4];  const float* vq_b0 = (const float*)d_in[5];
  const float* vq_w1 = (const float*)d_in[6];  const float* vq_b1 = (const float*)d_in[7];
  const float* cq_w0 = (const float*)d_in[8];  const float* cq_b0 = (const float*)d_in[9];
  const float* cq_w1 = (const float*)d_in[10]; const float* cq_b1 = (const float*)d_in[11];
  const float* cm_w0 = (const float*)d_in[12]; const float* cm_b0 = (const float*)d_in[13];
  const float* cm_w1 = (const float*)d_in[14]; const float* cm_b1 = (const float*)d_in[15];
  const float* ug_w0 = (const float*)d_in[16]; const float* ug_b0 = (const float*)d_in[17];
  const float* ug_w1 = (const float*)d_in[18]; const float* ug_b1 = (const float*)d_in[19];
  const float* ug_w2 = (const float*)d_in[20]; const float* ug_b2 = (const float*)d_in[21];
  const float* co_w0 = (const float*)d_in[22]; const float* co_b0 = (const float*)d_in[23];
  const float* co_w1 = (const float*)d_in[24]; const float* co_b1 = (const float*)d_in[25];
  float* out = (float*)d_out;

  char* base = (char*)d_ws;
  size_t off = 0;
  auto A = [&](size_t n) -> char* {
    char* p = base + off;
    off = (off + n + 255) & ~(size_t)255;
    return p;
  };
  // persistent + long-lived (f32)
  float* variables = (float*)A((size_t)NV * 128 * 4);
  float* clauses   = (float*)A((size_t)NC * 128 * 4);
  float* vq        = (float*)A((size_t)NV * 128 * 4);
  // shared lifetime regions
  char* R1 = A(12582912);  // hv f32 | cmh_chunk f32 (CMCHUNK x 256) | vgrad f32
  char* R2 = A(25165824);  // loss bf16 | lh bf16 | uh1 f32
  char* R3 = A(25165824);  // cg bf16 | uh2 f32
  char* R4 = A(25165824);  // hc bf16 | cd0 bf16 | uout f32
  char* R5 = A(25165824);  // cq bf16 | cd1 bf16
  bf16* gl = (bf16*)A((size_t)2 * NV * 128 * 2);
  bf16* vl = (bf16*)A((size_t)2 * NV * 128 * 2);
  int* cptr = (int*)A((size_t)(NC + 1) * 4);
  int* lptr = (int*)A((size_t)(2 * NV + 1) * 4);
  int* lcur = (int*)A((size_t)2 * NV * 4);
  int* lclause = (int*)A((size_t)NE * 4);
  float* dw  = (float*)A((size_t)2 * NV * 4);
  float* vdw = (float*)A((size_t)NV * 4);
  float* stats = (float*)A(2048);
  if (off > ws_size) {  // diagnostic: NaN-fill output so this is distinguishable
    hipMemsetAsync(d_out, 0xFF, (size_t)out_size * 4, stream);
    return;
  }
  float* hv = (float*)R1;  float* cmh = (float*)R1;  float* vgrad = (float*)R1;
  bf16* loss = (bf16*)R2;  bf16* lh = (bf16*)R2;     float* uh1 = (float*)R2;
  bf16* cg = (bf16*)R3;    float* uh2 = (float*)R3;
  bf16* hc = (bf16*)R4;    bf16* cd0 = (bf16*)R4;    float* uout = (float*)R4;
  bf16* cq = (bf16*)R5;    bf16* cd1 = (bf16*)R5;

  hipMemsetAsync(lcur, 0, (size_t)2 * NV * 4, stream);
  k_cptr<<<(NC + 1 + 255) / 256, 256, 0, stream>>>(edge_clause, cptr);
  k_litcnt<<<NE / 256, 256, 0, stream>>>(edge_lit, lcur);
  k_scan<<<1, 1024, 0, stream>>>(lcur, lptr);
  k_fillsort<<<NE / 256, 256, 0, stream>>>(edge_lit, edge_clause, lcur, lclause);
  k_degree<<<(2 * NV + 255) / 256, 256, 0, stream>>>(lptr, dw, vdw);
  k_fill1<<<NV * 128 / 256, 256, 0, stream>>>(variables);
  k_fill1<<<NC * 128 / 256, 256, 0, stream>>>(clauses);

  for (int t = 0; t < 4; ++t) {
    const float* nvp = noise_v + (size_t)t * NV * 4;
    const float* ncp = noise_c + (size_t)t * NC * 4;
    // vq = mlp2([variables, noise_v]) -> f32
    gemm_k<132, true,  L_VN,      false, false><<<dim3(NV / 64, 1), 256, 0, stream>>>(variables, nvp, nullptr, nullptr, vq_w0, vq_b0, hv, nullptr, 128, 128);
    gemm_k<128, false, L_PLAIN_F, false, false><<<dim3(NV / 64, 1), 256, 0, stream>>>(hv, nullptr, nullptr, nullptr, vq_w1, vq_b1, vq, nullptr, 128, 128);
    // cq = mlp2([clauses, noise_c]) -> bf16
    gemm_k<132, true,  L_VN,      true,  false><<<dim3(NC / 64, 1), 256, 0, stream>>>(clauses, ncp, nullptr, nullptr, cq_w0, cq_b0, hc, nullptr, 128, 128);
    gemm_k<128, false, L_PLAIN_H, true,  false><<<dim3(NC / 64, 1), 256, 0, stream>>>(hc, nullptr, nullptr, nullptr, cq_w1, cq_b1, cq, nullptr, 128, 128);
    // loss + cgrad-precursor
    k_loss<<<NC / 2, 256, 0, stream>>>(edge_lit, cptr, vq, cq, loss, cg);
    // clause_data = mlp2([clauses, 4*loss, cg]) — chunked hidden, split outputs
    for (int ch = 0; ch < NC / CMCHUNK; ++ch) {
      size_t ro = (size_t)ch * CMCHUNK;
      gemm_k<384, true,  L_CM,      false, false><<<dim3(CMCHUNK / 64, 2), 256, 0, stream>>>(clauses + ro * 128, loss + ro * 128, cg + ro * 128, nullptr, cm_w0, cm_b0, cmh, nullptr, 256, 256);
      gemm_k<256, false, L_PLAIN_F, true,  true ><<<dim3(CMCHUNK / 64, 2), 256, 0, stream>>>(cmh, nullptr, nullptr, nullptr, cm_w1, cm_b1, cd0 + ro * 128, cd1 + ro * 128, 256, 128);
    }
    // per-literal gathers
    k_gather<<<NV, 256, 0, stream>>>(lptr, lclause, loss, cd0, gl, vl);
    k_vgrad<<<NV * 128 / 256, 256, 0, stream>>>(vq, gl, vdw, vgrad);
    // clauses = pair_norm(cd1)*0.25 + 0.1*clauses
    hipMemsetAsync(stats, 0, 129 * 4, stream);
    k_pn_stats<bf16><<<256, 256, 0, stream>>>(cd1, NC, stats);
    k_pn_final<<<1, 128, 0, stream>>>(stats, (float)NC);
    k_pn_apply<bf16><<<NC * 128 / 256, 256, 0, stream>>>(cd1, stats, clauses);
    // logits from new clauses
    gemm_k<128, true, L_PLAIN_F, true, false><<<dim3(NC / 64, 1), 256, 0, stream>>>(clauses, nullptr, nullptr, nullptr, co_w0, co_b0, lh, nullptr, 128, 128);
    k_logits<<<NC / 4, 256, 0, stream>>>(lh, co_w1, co_b1, out, t);
    // variables = pair_norm(mlp3([vgrad, variables, vl*dw]))*0.25 + 0.1*variables
    gemm_k<512, true,  L_UG,      false, false><<<dim3(NV / 64, 2), 256, 0, stream>>>(vgrad, variables, vl, dw, ug_w0, ug_b0, uh1, nullptr, 256, 256);
    gemm_k<256, true,  L_PLAIN_F, false, false><<<dim3(NV / 64, 2), 256, 0, stream>>>(uh1, nullptr, nullptr, nullptr, ug_w1, ug_b1, uh2, nullptr, 256, 256);
    gemm_k<256, false, L_PLAIN_F, false, false><<<dim3(NV / 64, 1), 256, 0, stream>>>(uh2, nullptr, nullptr, nullptr, ug_w2, ug_b2, uout, nullptr, 128, 128);
    hipMemsetAsync(stats, 0, 129 * 4, stream);
    k_pn_stats<float><<<256, 256, 0, stream>>>(uout, NV, stats);
    k_pn_final<<<1, 128, 0, stream>>>(stats, (float)NV);
    k_pn_apply<float><<<NV * 128 / 256, 256, 0, stream>>>(uout, stats, variables);
  }
}

// Round 3
// 2368.399 us; speedup vs baseline: 2.6838x; 2.6838x over previous
//
#include <hip/hip_runtime.h>
#include <math.h>

#define NV 24576
#define NC 98304
#define NE 294912
#define CMCHUNK 24576  // 4 chunks over NC

typedef unsigned short bf16;
using bf8 = __attribute__((ext_vector_type(8))) short;
using f4  = __attribute__((ext_vector_type(4))) float;

static constexpr float INV_CQM = 1.0f / 12582912.0f;  // 1/(NC*128)

__device__ __forceinline__ float b2f(bf16 h) { return __uint_as_float(((unsigned)h) << 16); }
__device__ __forceinline__ bf16 f2b(float f) {
  unsigned u = __float_as_uint(f);
  u += 0x7fff + ((u >> 16) & 1);  // RNE
  return (bf16)(u >> 16);
}
__device__ __forceinline__ float dsigm(float x) { return 1.0f / (1.0f + expf(-x)); }
__device__ __forceinline__ float dsoftplus(float x) { return fmaxf(x, 0.0f) + log1pf(expf(-fabsf(x))); }
__device__ __forceinline__ float cvt_ld(float x) { return x; }
__device__ __forceinline__ float cvt_ld(bf16 x) { return b2f(x); }

// ---------------- precompute kernels ----------------

__global__ __launch_bounds__(256) void k_cptr(const int* __restrict__ ec, int* __restrict__ ptr) {
  int c = blockIdx.x * 256 + threadIdx.x;
  if (c > NC) return;
  int lo = 0, hi = NE;
  while (lo < hi) { int mid = (lo + hi) >> 1; if (ec[mid] < c) lo = mid + 1; else hi = mid; }
  ptr[c] = lo;
}

__global__ __launch_bounds__(256) void k_litcnt(const int* __restrict__ el, int* __restrict__ cnt) {
  int e = blockIdx.x * 256 + threadIdx.x;
  atomicAdd(&cnt[el[e]], 1);
}

__global__ __launch_bounds__(1024) void k_scan(int* __restrict__ cnt, int* __restrict__ ptr) {
  __shared__ int wsum[16];
  __shared__ int carry_s;
  int tid = threadIdx.x, lane = tid & 63, w = tid >> 6;
  if (tid == 0) carry_s = 0;
  __syncthreads();
  for (int base = 0; base < 2 * NV; base += 1024) {
    int x = cnt[base + tid];
    int v = x;
#pragma unroll
    for (int off = 1; off < 64; off <<= 1) {
      int y = __shfl_up(v, off, 64);
      if (lane >= off) v += y;
    }
    if (lane == 63) wsum[w] = v;
    __syncthreads();
    int carry = carry_s;
    int wpre = 0;
    for (int i = 0; i < w; ++i) wpre += wsum[i];
    int excl = carry + wpre + (v - x);
    ptr[base + tid] = excl;
    cnt[base + tid] = excl;
    __syncthreads();
    if (tid == 1023) carry_s = carry + wpre + v;
  }
  __syncthreads();
  if (tid == 0) ptr[2 * NV] = carry_s;
}

__global__ __launch_bounds__(256) void k_fillsort(const int* __restrict__ el, const int* __restrict__ ec,
                                                  int* __restrict__ cur, int* __restrict__ lclause) {
  int e = blockIdx.x * 256 + threadIdx.x;
  int pos = atomicAdd(&cur[el[e]], 1);
  lclause[pos] = ec[e];
}

__global__ __launch_bounds__(256) void k_degree(const int* __restrict__ lptr, float* __restrict__ dw,
                                                float* __restrict__ vdw) {
  int l = blockIdx.x * 256 + threadIdx.x;
  if (l < 2 * NV) dw[l] = rsqrtf(fmaxf((float)(lptr[l + 1] - lptr[l]), 1.0f));
  if (l < NV) {
    int d = (lptr[l + 1] - lptr[l]) + (lptr[l + NV + 1] - lptr[l + NV]);
    vdw[l] = 4.0f * rsqrtf(fmaxf((float)d, 1.0f));
  }
}

// init: variables f32 = 1, ugA variables-mirror = bf16(1)
__global__ __launch_bounds__(256) void k_init_v(float* __restrict__ variables, bf16* __restrict__ ugA) {
  int i = blockIdx.x * 256 + threadIdx.x;
  variables[i] = 1.0f;
  ugA[(size_t)(i >> 7) * 512 + 128 + (i & 127)] = 0x3F80;
}
__global__ __launch_bounds__(256) void k_init_c(bf16* __restrict__ cmA) {
  int i = blockIdx.x * 256 + threadIdx.x;
  cmA[(size_t)(i >> 7) * 384 + (i & 127)] = 0x3F80;
}

// transpose + bf16 convert weights: wt[n*Kpad+k] = w[k*N+n] (zero-pad k>=K)
__global__ __launch_bounds__(256) void k_wt(const float* __restrict__ w, bf16* __restrict__ wt,
                                            int K, int N, int Kpad) {
  int idx = blockIdx.x * 256 + threadIdx.x;
  int n = idx / Kpad, k = idx % Kpad;
  if (n >= N) return;
  wt[idx] = (k < K) ? f2b(w[(size_t)k * N + n]) : (bf16)0;
}

// ---------------- MFMA GEMM: 128x128 tile, 4 waves, BK=64, XOR-swizzled LDS ----------------
// A: bf16 row-major (lda elements). CONCAT: cols [0,128) from A0, [128,132) from noise f32, rest 0.
// WT: bf16 N x KDIM row-major (pre-transposed weights). OUT: 0=f32, 1=bf16, 2=dual bf16 split at col 128.

template <bool CONCAT, bool RELU, int OUT>
__global__ __launch_bounds__(256) void mgemm(const bf16* __restrict__ A0, int lda,
                                             const float* __restrict__ noise,
                                             const bf16* __restrict__ WT,
                                             const float* __restrict__ Bv,
                                             void* out0, void* out1, int ldOut, int KDIM) {
  __shared__ __align__(16) char smem[32768];
  char* As = smem;
  char* Bs = smem + 16384;
  const int tid = threadIdx.x;
  const int m0 = blockIdx.x * 128;
  const int n0 = blockIdx.y * 128;
  const int lane = tid & 63;
  const int w = tid >> 6;
  const int wr = w >> 1, wc = w & 1;
  const int srow = tid >> 3;   // 0..31
  const int schunk = tid & 7;  // 16B chunk
  f4 acc[4][4] = {};
  for (int k0 = 0; k0 < KDIM; k0 += 64) {
#pragma unroll
    for (int it = 0; it < 4; ++it) {
      int row = srow + it * 32;
      int kc = k0 + schunk * 8;
      uint4 aval;
      if (!CONCAT || k0 < 128) {
        aval = *reinterpret_cast<const uint4*>(&A0[(size_t)(m0 + row) * lda + kc]);
      } else {
        alignas(16) bf16 tmp[8];
#pragma unroll
        for (int e = 0; e < 8; ++e) {
          int kk = kc + e - 128;
          tmp[e] = (kk < 4) ? f2b(noise[(size_t)(m0 + row) * 4 + kk]) : (bf16)0;
        }
        aval = *reinterpret_cast<uint4*>(tmp);
      }
      *reinterpret_cast<uint4*>(&As[row * 128 + ((schunk * 16) ^ ((row & 7) << 4))]) = aval;
      uint4 bval = *reinterpret_cast<const uint4*>(&WT[(size_t)(n0 + row) * KDIM + kc]);
      *reinterpret_cast<uint4*>(&Bs[row * 128 + ((schunk * 16) ^ ((row & 7) << 4))]) = bval;
    }
    __syncthreads();
#pragma unroll
    for (int kk = 0; kk < 2; ++kk) {
      bf8 a[4], b[4];
#pragma unroll
      for (int i = 0; i < 4; ++i) {
        int r = wr * 64 + i * 16 + (lane & 15);
        int cby = (kk * 64 + ((lane >> 4) * 16)) ^ ((r & 7) << 4);
        a[i] = *reinterpret_cast<const bf8*>(&As[r * 128 + cby]);
        int c = wc * 64 + i * 16 + (lane & 15);
        int cby2 = (kk * 64 + ((lane >> 4) * 16)) ^ ((c & 7) << 4);
        b[i] = *reinterpret_cast<const bf8*>(&Bs[c * 128 + cby2]);
      }
#pragma unroll
      for (int i = 0; i < 4; ++i)
#pragma unroll
        for (int j = 0; j < 4; ++j)
          acc[i][j] = __builtin_amdgcn_mfma_f32_16x16x32_bf16(a[i], b[j], acc[i][j], 0, 0, 0);
    }
    __syncthreads();
  }
  // epilogue: C row = (lane>>4)*4 + reg, col = lane&15 (per-fragment), + i*16 / j*16 / wave offsets
  const int colloc = wc * 64 + (lane & 15);
  const int rowbase = m0 + wr * 64 + ((lane >> 4) << 2);
#pragma unroll
  for (int j = 0; j < 4; ++j) {
    int c = n0 + colloc + j * 16;
    float bias = Bv[c];
#pragma unroll
    for (int i = 0; i < 4; ++i) {
      int rb = rowbase + i * 16;
#pragma unroll
      for (int p = 0; p < 4; ++p) {
        float v = acc[i][j][p] + bias;
        if (RELU) v = fmaxf(v, 0.0f);
        int r = rb + p;
        if constexpr (OUT == 0) {
          ((float*)out0)[(size_t)r * ldOut + c] = v;
        } else if constexpr (OUT == 1) {
          ((bf16*)out0)[(size_t)r * ldOut + c] = f2b(v);
        } else {
          bf16* o = (c < 128) ? (bf16*)out0 : (bf16*)out1;
          o[(size_t)r * 128 + (c & 127)] = f2b(v);
        }
      }
    }
  }
}

// ---------------- graph / elementwise kernels ----------------

// per clause: loss4 = 4*exp(-csum)*sigm(cq), cg = loss*(1-sigm)*INV_CQM -> into cmA cols 128..384
__global__ __launch_bounds__(256) void k_loss(const int* __restrict__ edge_lit, const int* __restrict__ cptr,
                                              const float* __restrict__ vq, const bf16* __restrict__ cq,
                                              bf16* __restrict__ cmA) {
  int c = blockIdx.x * 2 + (threadIdx.x >> 7);
  int q = threadIdx.x & 127;
  int e0 = cptr[c], e1 = cptr[c + 1];
  float csum = 0.0f;
  for (int e = e0; e < e1; ++e) {
    int lit = edge_lit[e];
    float x = (lit < NV) ? vq[(size_t)lit * 128 + q] : -vq[(size_t)(lit - NV) * 128 + q];
    csum += dsoftplus(x);
  }
  float s = dsigm(b2f(cq[(size_t)c * 128 + q]));
  float L = expf(-csum) * s;
  cmA[(size_t)c * 384 + 128 + q] = f2b(4.0f * L);
  cmA[(size_t)c * 384 + 256 + q] = f2b(L * (1.0f - s) * INV_CQM);
}

// per literal: gl4 = sum loss4 rows; vl*dw -> ugA cols [256,384) (pos) / [384,512) (neg)
__global__ __launch_bounds__(256) void k_gather(const int* __restrict__ lptr, const int* __restrict__ lclause,
                                                const bf16* __restrict__ cmA, const bf16* __restrict__ cd0,
                                                bf16* __restrict__ gl, bf16* __restrict__ ugA,
                                                const float* __restrict__ dw) {
  int l = blockIdx.x * 2 + (threadIdx.x >> 7);
  int q = threadIdx.x & 127;
  int j0 = lptr[l], j1 = lptr[l + 1];
  float sg = 0.0f, sv = 0.0f;
  for (int j = j0; j < j1; ++j) {
    int c = lclause[j];
    sg += b2f(cmA[(size_t)c * 384 + 128 + q]);
    sv += b2f(cd0[(size_t)c * 128 + q]);
  }
  gl[(size_t)l * 128 + q] = f2b(sg);
  int r = (l < NV) ? l : l - NV;
  int cb = (l < NV) ? 256 : 384;
  ugA[(size_t)r * 512 + cb + q] = f2b(sv * dw[l]);
}

// vgrad -> ugA cols [0,128)
__global__ __launch_bounds__(256) void k_vgrad(const float* __restrict__ vq, const bf16* __restrict__ gl,
                                               const float* __restrict__ vdw, bf16* __restrict__ ugA) {
  int i = blockIdx.x * 256 + threadIdx.x;
  int v = i >> 7, q = i & 127;
  float x = vq[i];
  float gp = b2f(gl[(size_t)v * 128 + q]);
  float gn = b2f(gl[(size_t)(v + NV) * 128 + q]);
  float g = (dsigm(-x) * gn - dsigm(x) * gp) * (INV_CQM * 0.25f) * vdw[v];
  ugA[(size_t)v * 512 + q] = f2b(g);
}

template <typename T>
__global__ __launch_bounds__(256) void k_pn_stats(const T* __restrict__ X, int R, float* __restrict__ stats) {
  int q = threadIdx.x & 127;
  int rg = threadIdx.x >> 7;
  float cs = 0.0f, ss = 0.0f;
  for (int r = blockIdx.x * 2 + rg; r < R; r += gridDim.x * 2) {
    float x = cvt_ld(X[(size_t)r * 128 + q]);
    cs += x;
    ss += x * x;
  }
  __shared__ float scs[256], sss[256];
  scs[threadIdx.x] = cs;
  sss[threadIdx.x] = ss;
  __syncthreads();
  if (threadIdx.x < 128) atomicAdd(&stats[q], scs[q] + scs[128 + q]);
  for (int off = 128; off; off >>= 1) {
    if (threadIdx.x < off) sss[threadIdx.x] += sss[threadIdx.x + off];
    __syncthreads();
  }
  if (threadIdx.x == 0) atomicAdd(&stats[128], sss[0]);
}

__global__ __launch_bounds__(128) void k_pn_final(float* __restrict__ stats, float R) {
  __shared__ float s[128];
  int q = threadIdx.x;
  float m = stats[q] / R;
  s[q] = m * m;
  __syncthreads();
  for (int off = 64; off; off >>= 1) {
    if (q < off) s[q] += s[q + off];
    __syncthreads();
  }
  if (q == 0) {
    float var = (stats[128] - R * s[0]) / (R * 128.0f);
    stats[129] = rsqrtf(fmaxf(var, 0.0f) + 1e-6f) * 0.25f;
  }
  stats[q] = m;
}

// clauses state update in cmA cols [0,128): new = (cd1 - m)*s + 0.1*old
__global__ __launch_bounds__(256) void k_pn_apply_c(const bf16* __restrict__ cd1, const float* __restrict__ stats,
                                                    bf16* __restrict__ cmA) {
  int i = blockIdx.x * 256 + threadIdx.x;
  int c = i >> 7, q = i & 127;
  float x = b2f(cd1[i]);
  float old = b2f(cmA[(size_t)c * 384 + q]);
  cmA[(size_t)c * 384 + q] = f2b((x - stats[q]) * stats[129] + 0.1f * old);
}

// variables state update: f32 state + bf16 mirror in ugA cols [128,256)
__global__ __launch_bounds__(256) void k_pn_apply_v(const float* __restrict__ uout, const float* __restrict__ stats,
                                                    float* __restrict__ variables, bf16* __restrict__ ugA) {
  int i = blockIdx.x * 256 + threadIdx.x;
  int v = i >> 7, q = i & 127;
  float nv = (uout[i] - stats[q]) * stats[129] + 0.1f * variables[i];
  variables[i] = nv;
  ugA[(size_t)v * 512 + 128 + q] = f2b(nv);
}

__global__ __launch_bounds__(256) void k_logits(const bf16* __restrict__ lh, const float* __restrict__ w1,
                                                const float* __restrict__ b1, float* __restrict__ outp, int t) {
  int wv = threadIdx.x >> 6, lane = threadIdx.x & 63;
  int c = blockIdx.x * 4 + wv;
  const bf16* row = lh + (size_t)c * 128;
  float v = b2f(row[lane]) * w1[lane] + b2f(row[64 + lane]) * w1[64 + lane];
#pragma unroll
  for (int off = 32; off; off >>= 1) v += __shfl_down(v, off, 64);
  if (lane == 0) {
    float lg = v + b1[0];
    outp[(size_t)t * NC + c] = 1.0f / (1.0f + expf(-lg));
    outp[(size_t)4 * NC + (size_t)t * NC + c] = dsoftplus(lg);
  }
}

// ---------------- host ----------------

extern "C" void kernel_launch(void* const* d_in, const int* in_sizes, int n_in,
                              void* d_out, int out_size, void* d_ws, size_t ws_size,
                              hipStream_t stream) {
  const int* edge_lit = (const int*)d_in[0];
  const int* edge_clause = (const int*)d_in[1];
  const float* noise_v = (const float*)d_in[2];
  const float* noise_c = (const float*)d_in[3];
  const float* vq_w0 = (const float*)d_in[4];  const float* vq_b0 = (const float*)d_in[5];
  const float* vq_w1 = (const float*)d_in[6];  const float* vq_b1 = (const float*)d_in[7];
  const float* cq_w0 = (const float*)d_in[8];  const float* cq_b0 = (const float*)d_in[9];
  const float* cq_w1 = (const float*)d_in[10]; const float* cq_b1 = (const float*)d_in[11];
  const float* cm_w0 = (const float*)d_in[12]; const float* cm_b0 = (const float*)d_in[13];
  const float* cm_w1 = (const float*)d_in[14]; const float* cm_b1 = (const float*)d_in[15];
  const float* ug_w0 = (const float*)d_in[16]; const float* ug_b0 = (const float*)d_in[17];
  const float* ug_w1 = (const float*)d_in[18]; const float* ug_b1 = (const float*)d_in[19];
  const float* ug_w2 = (const float*)d_in[20]; const float* ug_b2 = (const float*)d_in[21];
  const float* co_w0 = (const float*)d_in[22]; const float* co_b0 = (const float*)d_in[23];
  const float* co_w1 = (const float*)d_in[24]; const float* co_b1 = (const float*)d_in[25];
  float* out = (float*)d_out;

  char* base = (char*)d_ws;
  size_t off = 0;
  auto A = [&](size_t n) -> char* {
    char* p = base + off;
    off = (off + n + 255) & ~(size_t)255;
    return p;
  };
  float* variables = (float*)A((size_t)NV * 128 * 4);   // 12.6MB
  float* vq        = (float*)A((size_t)NV * 128 * 4);   // 12.6MB
  bf16* cmA        = (bf16*)A((size_t)NC * 384 * 2);    // 75.5MB [clauses_h | loss4 | cg]
  bf16* ugA        = (bf16*)A((size_t)NV * 512 * 2);    // 25.2MB [vgrad | vars_h | vl_lo*dw | vl_hi*dw]
  char* R_cq       = A((size_t)NC * 128 * 2);           // 25.2MB cq | cd0 | lh
  char* R_h        = A((size_t)NC * 128 * 2);           // 25.2MB hv/hc | cd1 | uh1+uh2
  char* R_big      = A((size_t)2 * NV * 128 * 2 + (size_t)NV * 128 * 4);  // 25.2MB cmh | gl+uout
  bf16* wtb        = (bf16*)A(983424);
  int* cptr = (int*)A((size_t)(NC + 1) * 4);
  int* lptr = (int*)A((size_t)(2 * NV + 1) * 4);
  int* lcur = (int*)A((size_t)2 * NV * 4);
  int* lclause = (int*)A((size_t)NE * 4);
  float* dw  = (float*)A((size_t)2 * NV * 4);
  float* vdw = (float*)A((size_t)NV * 4);
  float* stats = (float*)A(2048);
  if (off > ws_size) {
    hipMemsetAsync(d_out, 0xFF, (size_t)out_size * 4, stream);
    return;
  }

  bf16* cq  = (bf16*)R_cq;
  bf16* cd0 = (bf16*)R_cq;
  bf16* lh  = (bf16*)R_cq;
  bf16* hv  = (bf16*)R_h;
  bf16* hc  = (bf16*)R_h;
  bf16* cd1 = (bf16*)R_h;
  bf16* uh1 = (bf16*)R_h;
  bf16* uh2 = (bf16*)(R_h + (size_t)NV * 256 * 2);
  bf16* cmh = (bf16*)R_big;
  bf16* gl  = (bf16*)R_big;
  float* uout = (float*)(R_big + (size_t)2 * NV * 128 * 2);

  // weight transposes (bf16, K padded)
  size_t wo = 0;
  auto WTa = [&](int n, int kp) { bf16* p = wtb + wo; wo += (size_t)n * kp; return p; };
  bf16* wt_vq0 = WTa(128, 192); bf16* wt_vq1 = WTa(128, 128);
  bf16* wt_cq0 = WTa(128, 192); bf16* wt_cq1 = WTa(128, 128);
  bf16* wt_cm0 = WTa(256, 384); bf16* wt_cm1 = WTa(256, 256);
  bf16* wt_ug0 = WTa(256, 512); bf16* wt_ug1 = WTa(256, 256);
  bf16* wt_ug2 = WTa(128, 256); bf16* wt_co0 = WTa(128, 128);

  hipMemsetAsync(lcur, 0, (size_t)2 * NV * 4, stream);
  k_cptr<<<(NC + 256) / 256, 256, 0, stream>>>(edge_clause, cptr);
  k_litcnt<<<NE / 256, 256, 0, stream>>>(edge_lit, lcur);
  k_scan<<<1, 1024, 0, stream>>>(lcur, lptr);
  k_fillsort<<<NE / 256, 256, 0, stream>>>(edge_lit, edge_clause, lcur, lclause);
  k_degree<<<(2 * NV + 255) / 256, 256, 0, stream>>>(lptr, dw, vdw);
  k_init_v<<<NV * 128 / 256, 256, 0, stream>>>(variables, ugA);
  k_init_c<<<NC * 128 / 256, 256, 0, stream>>>(cmA);
  k_wt<<<128 * 192 / 256, 256, 0, stream>>>(vq_w0, wt_vq0, 132, 128, 192);
  k_wt<<<128 * 128 / 256, 256, 0, stream>>>(vq_w1, wt_vq1, 128, 128, 128);
  k_wt<<<128 * 192 / 256, 256, 0, stream>>>(cq_w0, wt_cq0, 132, 128, 192);
  k_wt<<<128 * 128 / 256, 256, 0, stream>>>(cq_w1, wt_cq1, 128, 128, 128);
  k_wt<<<256 * 384 / 256, 256, 0, stream>>>(cm_w0, wt_cm0, 384, 256, 384);
  k_wt<<<256 * 256 / 256, 256, 0, stream>>>(cm_w1, wt_cm1, 256, 256, 256);
  k_wt<<<256 * 512 / 256, 256, 0, stream>>>(ug_w0, wt_ug0, 512, 256, 512);
  k_wt<<<256 * 256 / 256, 256, 0, stream>>>(ug_w1, wt_ug1, 256, 256, 256);
  k_wt<<<128 * 256 / 256, 256, 0, stream>>>(ug_w2, wt_ug2, 256, 128, 256);
  k_wt<<<128 * 128 / 256, 256, 0, stream>>>(co_w0, wt_co0, 128, 128, 128);

  for (int t = 0; t < 4; ++t) {
    const float* nvp = noise_v + (size_t)t * NV * 4;
    const float* ncp = noise_c + (size_t)t * NC * 4;
    // vq = mlp2([variables, nv])  (A = ugA vars mirror)
    mgemm<true, true, 1><<<dim3(NV / 128, 1), 256, 0, stream>>>(ugA + 128, 512, nvp, wt_vq0, vq_b0, hv, nullptr, 128, 192);
    mgemm<false, false, 0><<<dim3(NV / 128, 1), 256, 0, stream>>>(hv, 128, nullptr, wt_vq1, vq_b1, vq, nullptr, 128, 128);
    // cq = mlp2([clauses, nc])  (A = cmA clause mirror)
    mgemm<true, true, 1><<<dim3(NC / 128, 1), 256, 0, stream>>>(cmA, 384, ncp, wt_cq0, cq_b0, hc, nullptr, 128, 192);
    mgemm<false, false, 1><<<dim3(NC / 128, 1), 256, 0, stream>>>(hc, 128, nullptr, wt_cq1, cq_b1, cq, nullptr, 128, 128);
    // loss4 + cg into cmA
    k_loss<<<NC / 2, 256, 0, stream>>>(edge_lit, cptr, vq, cq, cmA);
    // clause_data = mlp2(cmA) — chunked
    for (int ch = 0; ch < NC / CMCHUNK; ++ch) {
      size_t ro = (size_t)ch * CMCHUNK;
      mgemm<false, true, 1><<<dim3(CMCHUNK / 128, 2), 256, 0, stream>>>(cmA + ro * 384, 384, nullptr, wt_cm0, cm_b0, cmh, nullptr, 256, 384);
      mgemm<false, false, 2><<<dim3(CMCHUNK / 128, 2), 256, 0, stream>>>(cmh, 256, nullptr, wt_cm1, cm_b1, cd0 + ro * 128, cd1 + ro * 128, 128, 256);
    }
    // gathers + vgrad
    k_gather<<<NV, 256, 0, stream>>>(lptr, lclause, cmA, cd0, gl, ugA, dw);
    k_vgrad<<<NV * 128 / 256, 256, 0, stream>>>(vq, gl, vdw, ugA);
    // clauses = pair_norm(cd1)*0.25 + 0.1*clauses  (in cmA mirror)
    hipMemsetAsync(stats, 0, 132 * 4, stream);
    k_pn_stats<bf16><<<256, 256, 0, stream>>>(cd1, NC, stats);
    k_pn_final<<<1, 128, 0, stream>>>(stats, (float)NC);
    k_pn_apply_c<<<NC * 128 / 256, 256, 0, stream>>>(cd1, stats, cmA);
    // logits head on new clauses
    mgemm<false, true, 1><<<dim3(NC / 128, 1), 256, 0, stream>>>(cmA, 384, nullptr, wt_co0, co_b0, lh, nullptr, 128, 128);
    k_logits<<<NC / 4, 256, 0, stream>>>(lh, co_w1, co_b1, out, t);
    // variables = pair_norm(mlp3(ugA))*0.25 + 0.1*variables
    mgemm<false, true, 1><<<dim3(NV / 128, 2), 256, 0, stream>>>(ugA, 512, nullptr, wt_ug0, ug_b0, uh1, nullptr, 256, 512);
    mgemm<false, true, 1><<<dim3(NV / 128, 2), 256, 0, stream>>>(uh1, 256, nullptr, wt_ug1, ug_b1, uh2, nullptr, 256, 256);
    mgemm<false, false, 0><<<dim3(NV / 128, 1), 256, 0, stream>>>(uh2, 256, nullptr, wt_ug2, ug_b2, uout, nullptr, 128, 256);
    hipMemsetAsync(stats, 0, 132 * 4, stream);
    k_pn_stats<float><<<256, 256, 0, stream>>>(uout, NV, stats);
    k_pn_final<<<1, 128, 0, stream>>>(stats, (float)NV);
    k_pn_apply_v<<<NV * 128 / 256, 256, 0, stream>>>(uout, stats, variables, ugA);
  }
}

// Round 4
// 2104.168 us; speedup vs baseline: 3.0208x; 1.1256x over previous
//
#include <hip/hip_runtime.h>
#include <math.h>

#define NV 24576
#define NC 98304
#define NE 294912
#define CMCHUNK 24576  // 4 chunks over NC

typedef unsigned short bf16;
using bf8 = __attribute__((ext_vector_type(8))) short;
using f4  = __attribute__((ext_vector_type(4))) float;

static constexpr float INV_CQM = 1.0f / 12582912.0f;  // 1/(NC*128)
static constexpr float LOG2E = 1.44269504f;
static constexpr float LN2 = 0.69314718f;

__device__ __forceinline__ float b2f(bf16 h) { return __uint_as_float(((unsigned)h) << 16); }
__device__ __forceinline__ bf16 f2b(float f) {
  unsigned u = __float_as_uint(f);
  u += 0x7fff + ((u >> 16) & 1);  // RNE
  return (bf16)(u >> 16);
}
// fast transcendentals: v_exp_f32 = 2^x, v_log_f32 = log2(x), v_rcp_f32 ~1ulp
__device__ __forceinline__ float fexp2(float x) { float r; asm("v_exp_f32 %0, %1" : "=v"(r) : "v"(x)); return r; }
__device__ __forceinline__ float flog2(float x) { float r; asm("v_log_f32 %0, %1" : "=v"(r) : "v"(x)); return r; }
__device__ __forceinline__ float frcpf(float x) { float r; asm("v_rcp_f32 %0, %1" : "=v"(r) : "v"(x)); return r; }
__device__ __forceinline__ float fsigm(float x) { return frcpf(1.0f + fexp2(-x * LOG2E)); }
__device__ __forceinline__ float fsoftplus(float x) {
  return fmaxf(x, 0.0f) + LN2 * flog2(1.0f + fexp2(-fabsf(x) * LOG2E));
}
__device__ __forceinline__ float cvt_ld(float x) { return x; }
__device__ __forceinline__ float cvt_ld(bf16 x) { return b2f(x); }

// direct global->LDS 16B DMA (lds dest: wave-uniform base + lane*16)
__device__ __forceinline__ void gload16(const void* g, void* l) {
  __builtin_amdgcn_global_load_lds((const __attribute__((address_space(1))) unsigned int*)g,
                                   (__attribute__((address_space(3))) unsigned int*)l, 16, 0, 0);
}

// ---------------- precompute kernels ----------------

__global__ __launch_bounds__(256) void k_cptr(const int* __restrict__ ec, int* __restrict__ ptr) {
  int c = blockIdx.x * 256 + threadIdx.x;
  if (c > NC) return;
  int lo = 0, hi = NE;
  while (lo < hi) { int mid = (lo + hi) >> 1; if (ec[mid] < c) lo = mid + 1; else hi = mid; }
  ptr[c] = lo;
}

__global__ __launch_bounds__(256) void k_litcnt(const int* __restrict__ el, int* __restrict__ cnt) {
  int e = blockIdx.x * 256 + threadIdx.x;
  atomicAdd(&cnt[el[e]], 1);
}

__global__ __launch_bounds__(1024) void k_scan(int* __restrict__ cnt, int* __restrict__ ptr) {
  __shared__ int wsum[16];
  __shared__ int carry_s;
  int tid = threadIdx.x, lane = tid & 63, w = tid >> 6;
  if (tid == 0) carry_s = 0;
  __syncthreads();
  for (int base = 0; base < 2 * NV; base += 1024) {
    int x = cnt[base + tid];
    int v = x;
#pragma unroll
    for (int off = 1; off < 64; off <<= 1) {
      int y = __shfl_up(v, off, 64);
      if (lane >= off) v += y;
    }
    if (lane == 63) wsum[w] = v;
    __syncthreads();
    int carry = carry_s;
    int wpre = 0;
    for (int i = 0; i < w; ++i) wpre += wsum[i];
    int excl = carry + wpre + (v - x);
    ptr[base + tid] = excl;
    cnt[base + tid] = excl;
    __syncthreads();
    if (tid == 1023) carry_s = carry + wpre + v;
  }
  __syncthreads();
  if (tid == 0) ptr[2 * NV] = carry_s;
}

__global__ __launch_bounds__(256) void k_fillsort(const int* __restrict__ el, const int* __restrict__ ec,
                                                  int* __restrict__ cur, int* __restrict__ lclause) {
  int e = blockIdx.x * 256 + threadIdx.x;
  int pos = atomicAdd(&cur[el[e]], 1);
  lclause[pos] = ec[e];
}

__global__ __launch_bounds__(256) void k_degree(const int* __restrict__ lptr, float* __restrict__ dw,
                                                float* __restrict__ vdw) {
  int l = blockIdx.x * 256 + threadIdx.x;
  if (l < 2 * NV) dw[l] = rsqrtf(fmaxf((float)(lptr[l + 1] - lptr[l]), 1.0f));
  if (l < NV) {
    int d = (lptr[l + 1] - lptr[l]) + (lptr[l + NV + 1] - lptr[l + NV]);
    vdw[l] = 4.0f * rsqrtf(fmaxf((float)d, 1.0f));
  }
}

__global__ __launch_bounds__(256) void k_init_v(float* __restrict__ variables, bf16* __restrict__ ugA) {
  int i = blockIdx.x * 256 + threadIdx.x;
  variables[i] = 1.0f;
  ugA[(size_t)(i >> 7) * 512 + 128 + (i & 127)] = 0x3F80;
}
__global__ __launch_bounds__(256) void k_init_c(bf16* __restrict__ cmA) {
  int i = blockIdx.x * 256 + threadIdx.x;
  cmA[(size_t)(i >> 7) * 384 + (i & 127)] = 0x3F80;
}

// transpose + bf16 convert weights: wt[n*Kpad+k] = w[k*N+n] (zero-pad k>=K)
__global__ __launch_bounds__(256) void k_wt(const float* __restrict__ w, bf16* __restrict__ wt,
                                            int K, int N, int Kpad) {
  int idx = blockIdx.x * 256 + threadIdx.x;
  int n = idx / Kpad, k = idx % Kpad;
  if (n >= N) return;
  wt[idx] = (k < K) ? f2b(w[(size_t)k * N + n]) : (bf16)0;
}

// ---------------- MFMA GEMM: 128x128 tile, 4 waves, BK=64 ----------------
// LDS linear via global_load_lds; XOR swizzle applied on the GLOBAL source address
// (involution: byte ^ ((row&7)<<4)), read path swizzled identically.
// A: bf16 row-major (lda elements). CONCAT: cols [0,128) from A0, [128,132) noise f32, rest 0.
// WT: bf16 N x KDIM row-major. OUT: 0=f32, 1=bf16, 2=dual bf16 split at col 128.

template <bool CONCAT, bool RELU, int OUT>
__global__ __launch_bounds__(256) void mgemm(const bf16* __restrict__ A0, int lda,
                                             const float* __restrict__ noise,
                                             const bf16* __restrict__ WT,
                                             const float* __restrict__ Bv,
                                             void* out0, void* out1, int ldOut, int KDIM) {
  __shared__ __align__(16) char smem[32768];
  char* As = smem;
  char* Bs = smem + 16384;
  const int tid = threadIdx.x;
  const int m0 = blockIdx.x * 128;
  const int n0 = blockIdx.y * 128;
  const int lane = tid & 63;
  const int w = tid >> 6;
  const int wr = w >> 1, wc = w & 1;
  const int rl = (tid >> 3) & 7;  // row within wave's 8-row staging group
  const int cc = tid & 7;         // 16B chunk
  const int swzoff = (cc * 16) ^ (rl << 4);  // pre-swizzled source byte offset
  f4 acc[4][4] = {};
  for (int k0 = 0; k0 < KDIM; k0 += 64) {
    if (!CONCAT || k0 < 128) {
#pragma unroll
      for (int it = 0; it < 4; ++it) {
        int row0 = it * 32 + w * 8;        // wave-uniform
        int row = row0 + rl;               // row&7 == rl
        gload16((const char*)(A0 + (size_t)(m0 + row) * lda + k0) + swzoff, As + row0 * 128);
        gload16((const char*)(WT + (size_t)(n0 + row) * KDIM + k0) + swzoff, Bs + row0 * 128);
      }
    } else {  // noise columns (k0==128): reg-stage A with swizzled LDS write, gload B
      const int srow = tid >> 3, schunk = tid & 7;
#pragma unroll
      for (int it = 0; it < 4; ++it) {
        int row = srow + it * 32;
        alignas(16) bf16 tmp[8];
#pragma unroll
        for (int e = 0; e < 8; ++e) {
          int kk = schunk * 8 + e;
          tmp[e] = (kk < 4) ? f2b(noise[(size_t)(m0 + row) * 4 + kk]) : (bf16)0;
        }
        *reinterpret_cast<uint4*>(&As[row * 128 + ((schunk * 16) ^ ((row & 7) << 4))]) =
            *reinterpret_cast<uint4*>(tmp);
        int row0 = it * 32 + w * 8;
        gload16((const char*)(WT + (size_t)(n0 + row0 + rl) * KDIM + k0) + swzoff, Bs + row0 * 128);
      }
    }
    __syncthreads();
#pragma unroll
    for (int kk = 0; kk < 2; ++kk) {
      bf8 a[4], b[4];
#pragma unroll
      for (int i = 0; i < 4; ++i) {
        int r = wr * 64 + i * 16 + (lane & 15);
        int cby = (kk * 64 + ((lane >> 4) * 16)) ^ ((r & 7) << 4);
        a[i] = *reinterpret_cast<const bf8*>(&As[r * 128 + cby]);
        int c = wc * 64 + i * 16 + (lane & 15);
        int cby2 = (kk * 64 + ((lane >> 4) * 16)) ^ ((c & 7) << 4);
        b[i] = *reinterpret_cast<const bf8*>(&Bs[c * 128 + cby2]);
      }
#pragma unroll
      for (int i = 0; i < 4; ++i)
#pragma unroll
        for (int j = 0; j < 4; ++j)
          acc[i][j] = __builtin_amdgcn_mfma_f32_16x16x32_bf16(a[i], b[j], acc[i][j], 0, 0, 0);
    }
    __syncthreads();
  }
  const int colloc = wc * 64 + (lane & 15);
  const int rowbase = m0 + wr * 64 + ((lane >> 4) << 2);
#pragma unroll
  for (int j = 0; j < 4; ++j) {
    int c = n0 + colloc + j * 16;
    float bias = Bv[c];
#pragma unroll
    for (int i = 0; i < 4; ++i) {
      int rb = rowbase + i * 16;
#pragma unroll
      for (int p = 0; p < 4; ++p) {
        float v = acc[i][j][p] + bias;
        if (RELU) v = fmaxf(v, 0.0f);
        int r = rb + p;
        if constexpr (OUT == 0) {
          ((float*)out0)[(size_t)r * ldOut + c] = v;
        } else if constexpr (OUT == 1) {
          ((bf16*)out0)[(size_t)r * ldOut + c] = f2b(v);
        } else {
          bf16* o = (c < 128) ? (bf16*)out0 : (bf16*)out1;
          o[(size_t)r * 128 + (c & 127)] = f2b(v);
        }
      }
    }
  }
}

// ---------------- graph / elementwise kernels ----------------

// per clause: loss4 = 4*exp(-csum)*sigm(cq), cg = loss*(1-sigm)*INV_CQM -> cmA cols 128..384
__global__ __launch_bounds__(256) void k_loss(const int* __restrict__ edge_lit, const int* __restrict__ cptr,
                                              const float* __restrict__ vq, const bf16* __restrict__ cq,
                                              bf16* __restrict__ cmA) {
  int c = blockIdx.x * 2 + (threadIdx.x >> 7);
  int q = threadIdx.x & 127;
  int e0 = cptr[c], e1 = cptr[c + 1];
  float csum = 0.0f;
  for (int e = e0; e < e1; ++e) {
    int lit = edge_lit[e];
    float x = (lit < NV) ? vq[(size_t)lit * 128 + q] : -vq[(size_t)(lit - NV) * 128 + q];
    csum += fsoftplus(x);
  }
  float s = fsigm(b2f(cq[(size_t)c * 128 + q]));
  float L = fexp2(-csum * LOG2E) * s;
  cmA[(size_t)c * 384 + 128 + q] = f2b(4.0f * L);
  cmA[(size_t)c * 384 + 256 + q] = f2b(L * (1.0f - s) * INV_CQM);
}

// per literal: gl4 = sum loss4 rows; vl*dw -> ugA cols [256,384) (pos) / [384,512) (neg)
__global__ __launch_bounds__(256) void k_gather(const int* __restrict__ lptr, const int* __restrict__ lclause,
                                                const bf16* __restrict__ cmA, const bf16* __restrict__ cd0,
                                                bf16* __restrict__ gl, bf16* __restrict__ ugA,
                                                const float* __restrict__ dw) {
  int l = blockIdx.x * 2 + (threadIdx.x >> 7);
  int q = threadIdx.x & 127;
  int j0 = lptr[l], j1 = lptr[l + 1];
  float sg = 0.0f, sv = 0.0f;
  for (int j = j0; j < j1; ++j) {
    int c = lclause[j];
    sg += b2f(cmA[(size_t)c * 384 + 128 + q]);
    sv += b2f(cd0[(size_t)c * 128 + q]);
  }
  gl[(size_t)l * 128 + q] = f2b(sg);
  int r = (l < NV) ? l : l - NV;
  int cb = (l < NV) ? 256 : 384;
  ugA[(size_t)r * 512 + cb + q] = f2b(sv * dw[l]);
}

// vgrad -> ugA cols [0,128)
__global__ __launch_bounds__(256) void k_vgrad(const float* __restrict__ vq, const bf16* __restrict__ gl,
                                               const float* __restrict__ vdw, bf16* __restrict__ ugA) {
  int i = blockIdx.x * 256 + threadIdx.x;
  int v = i >> 7, q = i & 127;
  float s = fsigm(vq[i]);
  float gp = b2f(gl[(size_t)v * 128 + q]);
  float gn = b2f(gl[(size_t)(v + NV) * 128 + q]);
  float g = ((1.0f - s) * gn - s * gp) * (INV_CQM * 0.25f) * vdw[v];
  ugA[(size_t)v * 512 + q] = f2b(g);
}

template <typename T>
__global__ __launch_bounds__(256) void k_pn_stats(const T* __restrict__ X, int R, float* __restrict__ stats) {
  int q = threadIdx.x & 127;
  int rg = threadIdx.x >> 7;
  float cs = 0.0f, ss = 0.0f;
  for (int r = blockIdx.x * 2 + rg; r < R; r += gridDim.x * 2) {
    float x = cvt_ld(X[(size_t)r * 128 + q]);
    cs += x;
    ss += x * x;
  }
  __shared__ float scs[256], sss[256];
  scs[threadIdx.x] = cs;
  sss[threadIdx.x] = ss;
  __syncthreads();
  if (threadIdx.x < 128) atomicAdd(&stats[q], scs[q] + scs[128 + q]);
  for (int off = 128; off; off >>= 1) {
    if (threadIdx.x < off) sss[threadIdx.x] += sss[threadIdx.x + off];
    __syncthreads();
  }
  if (threadIdx.x == 0) atomicAdd(&stats[128], sss[0]);
}

__global__ __launch_bounds__(128) void k_pn_final(float* __restrict__ stats, float R) {
  __shared__ float s[128];
  int q = threadIdx.x;
  float m = stats[q] / R;
  s[q] = m * m;
  __syncthreads();
  for (int off = 64; off; off >>= 1) {
    if (q < off) s[q] += s[q + off];
    __syncthreads();
  }
  if (q == 0) {
    float var = (stats[128] - R * s[0]) / (R * 128.0f);
    stats[129] = rsqrtf(fmaxf(var, 0.0f) + 1e-6f) * 0.25f;
  }
  stats[q] = m;
}

__global__ __launch_bounds__(256) void k_pn_apply_c(const bf16* __restrict__ cd1, const float* __restrict__ stats,
                                                    bf16* __restrict__ cmA) {
  int i = blockIdx.x * 256 + threadIdx.x;
  int c = i >> 7, q = i & 127;
  float x = b2f(cd1[i]);
  float old = b2f(cmA[(size_t)c * 384 + q]);
  cmA[(size_t)c * 384 + q] = f2b((x - stats[q]) * stats[129] + 0.1f * old);
}

__global__ __launch_bounds__(256) void k_pn_apply_v(const float* __restrict__ uout, const float* __restrict__ stats,
                                                    float* __restrict__ variables, bf16* __restrict__ ugA) {
  int i = blockIdx.x * 256 + threadIdx.x;
  int v = i >> 7, q = i & 127;
  float nv = (uout[i] - stats[q]) * stats[129] + 0.1f * variables[i];
  variables[i] = nv;
  ugA[(size_t)v * 512 + 128 + q] = f2b(nv);
}

__global__ __launch_bounds__(256) void k_logits(const bf16* __restrict__ lh, const float* __restrict__ w1,
                                                const float* __restrict__ b1, float* __restrict__ outp, int t) {
  int wv = threadIdx.x >> 6, lane = threadIdx.x & 63;
  int c = blockIdx.x * 4 + wv;
  const bf16* row = lh + (size_t)c * 128;
  float v = b2f(row[lane]) * w1[lane] + b2f(row[64 + lane]) * w1[64 + lane];
#pragma unroll
  for (int off = 32; off; off >>= 1) v += __shfl_down(v, off, 64);
  if (lane == 0) {
    float lg = v + b1[0];
    outp[(size_t)t * NC + c] = fsigm(lg);
    outp[(size_t)4 * NC + (size_t)t * NC + c] = fsoftplus(lg);
  }
}

// ---------------- host ----------------

extern "C" void kernel_launch(void* const* d_in, const int* in_sizes, int n_in,
                              void* d_out, int out_size, void* d_ws, size_t ws_size,
                              hipStream_t stream) {
  const int* edge_lit = (const int*)d_in[0];
  const int* edge_clause = (const int*)d_in[1];
  const float* noise_v = (const float*)d_in[2];
  const float* noise_c = (const float*)d_in[3];
  const float* vq_w0 = (const float*)d_in[4];  const float* vq_b0 = (const float*)d_in[5];
  const float* vq_w1 = (const float*)d_in[6];  const float* vq_b1 = (const float*)d_in[7];
  const float* cq_w0 = (const float*)d_in[8];  const float* cq_b0 = (const float*)d_in[9];
  const float* cq_w1 = (const float*)d_in[10]; const float* cq_b1 = (const float*)d_in[11];
  const float* cm_w0 = (const float*)d_in[12]; const float* cm_b0 = (const float*)d_in[13];
  const float* cm_w1 = (const float*)d_in[14]; const float* cm_b1 = (const float*)d_in[15];
  const float* ug_w0 = (const float*)d_in[16]; const float* ug_b0 = (const float*)d_in[17];
  const float* ug_w1 = (const float*)d_in[18]; const float* ug_b1 = (const float*)d_in[19];
  const float* ug_w2 = (const float*)d_in[20]; const float* ug_b2 = (const float*)d_in[21];
  const float* co_w0 = (const float*)d_in[22]; const float* co_b0 = (const float*)d_in[23];
  const float* co_w1 = (const float*)d_in[24]; const float* co_b1 = (const float*)d_in[25];
  float* out = (float*)d_out;

  char* base = (char*)d_ws;
  size_t off = 0;
  auto A = [&](size_t n) -> char* {
    char* p = base + off;
    off = (off + n + 255) & ~(size_t)255;
    return p;
  };
  float* variables = (float*)A((size_t)NV * 128 * 4);
  float* vq        = (float*)A((size_t)NV * 128 * 4);
  bf16* cmA        = (bf16*)A((size_t)NC * 384 * 2);    // [clauses_h | loss4 | cg]
  bf16* ugA        = (bf16*)A((size_t)NV * 512 * 2);    // [vgrad | vars_h | vl_lo*dw | vl_hi*dw]
  char* R_cq       = A((size_t)NC * 128 * 2);           // cq | cd0 | lh
  char* R_h        = A((size_t)NC * 128 * 2);           // hv/hc | cd1 | uh1+uh2
  char* R_big      = A((size_t)2 * NV * 128 * 2 + (size_t)NV * 128 * 4);  // cmh | gl + uout
  bf16* wtb        = (bf16*)A(983424);
  int* cptr = (int*)A((size_t)(NC + 1) * 4);
  int* lptr = (int*)A((size_t)(2 * NV + 1) * 4);
  int* lcur = (int*)A((size_t)2 * NV * 4);
  int* lclause = (int*)A((size_t)NE * 4);
  float* dw  = (float*)A((size_t)2 * NV * 4);
  float* vdw = (float*)A((size_t)NV * 4);
  float* stats = (float*)A(2048);
  if (off > ws_size) {
    hipMemsetAsync(d_out, 0xFF, (size_t)out_size * 4, stream);
    return;
  }

  bf16* cq  = (bf16*)R_cq;
  bf16* cd0 = (bf16*)R_cq;
  bf16* lh  = (bf16*)R_cq;
  bf16* hv  = (bf16*)R_h;
  bf16* hc  = (bf16*)R_h;
  bf16* cd1 = (bf16*)R_h;
  bf16* uh1 = (bf16*)R_h;
  bf16* uh2 = (bf16*)(R_h + (size_t)NV * 256 * 2);
  bf16* cmh = (bf16*)R_big;
  bf16* gl  = (bf16*)R_big;
  float* uout = (float*)(R_big + (size_t)2 * NV * 128 * 2);

  size_t wo = 0;
  auto WTa = [&](int n, int kp) { bf16* p = wtb + wo; wo += (size_t)n * kp; return p; };
  bf16* wt_vq0 = WTa(128, 192); bf16* wt_vq1 = WTa(128, 128);
  bf16* wt_cq0 = WTa(128, 192); bf16* wt_cq1 = WTa(128, 128);
  bf16* wt_cm0 = WTa(256, 384); bf16* wt_cm1 = WTa(256, 256);
  bf16* wt_ug0 = WTa(256, 512); bf16* wt_ug1 = WTa(256, 256);
  bf16* wt_ug2 = WTa(128, 256); bf16* wt_co0 = WTa(128, 128);

  hipMemsetAsync(lcur, 0, (size_t)2 * NV * 4, stream);
  k_cptr<<<(NC + 256) / 256, 256, 0, stream>>>(edge_clause, cptr);
  k_litcnt<<<NE / 256, 256, 0, stream>>>(edge_lit, lcur);
  k_scan<<<1, 1024, 0, stream>>>(lcur, lptr);
  k_fillsort<<<NE / 256, 256, 0, stream>>>(edge_lit, edge_clause, lcur, lclause);
  k_degree<<<(2 * NV + 255) / 256, 256, 0, stream>>>(lptr, dw, vdw);
  k_init_v<<<NV * 128 / 256, 256, 0, stream>>>(variables, ugA);
  k_init_c<<<NC * 128 / 256, 256, 0, stream>>>(cmA);
  k_wt<<<128 * 192 / 256, 256, 0, stream>>>(vq_w0, wt_vq0, 132, 128, 192);
  k_wt<<<128 * 128 / 256, 256, 0, stream>>>(vq_w1, wt_vq1, 128, 128, 128);
  k_wt<<<128 * 192 / 256, 256, 0, stream>>>(cq_w0, wt_cq0, 132, 128, 192);
  k_wt<<<128 * 128 / 256, 256, 0, stream>>>(cq_w1, wt_cq1, 128, 128, 128);
  k_wt<<<256 * 384 / 256, 256, 0, stream>>>(cm_w0, wt_cm0, 384, 256, 384);
  k_wt<<<256 * 256 / 256, 256, 0, stream>>>(cm_w1, wt_cm1, 256, 256, 256);
  k_wt<<<256 * 512 / 256, 256, 0, stream>>>(ug_w0, wt_ug0, 512, 256, 512);
  k_wt<<<256 * 256 / 256, 256, 0, stream>>>(ug_w1, wt_ug1, 256, 256, 256);
  k_wt<<<128 * 256 / 256, 256, 0, stream>>>(ug_w2, wt_ug2, 256, 128, 256);
  k_wt<<<128 * 128 / 256, 256, 0, stream>>>(co_w0, wt_co0, 128, 128, 128);

  for (int t = 0; t < 4; ++t) {
    const float* nvp = noise_v + (size_t)t * NV * 4;
    const float* ncp = noise_c + (size_t)t * NC * 4;
    mgemm<true, true, 1><<<dim3(NV / 128, 1), 256, 0, stream>>>(ugA + 128, 512, nvp, wt_vq0, vq_b0, hv, nullptr, 128, 192);
    mgemm<false, false, 0><<<dim3(NV / 128, 1), 256, 0, stream>>>(hv, 128, nullptr, wt_vq1, vq_b1, vq, nullptr, 128, 128);
    mgemm<true, true, 1><<<dim3(NC / 128, 1), 256, 0, stream>>>(cmA, 384, ncp, wt_cq0, cq_b0, hc, nullptr, 128, 192);
    mgemm<false, false, 1><<<dim3(NC / 128, 1), 256, 0, stream>>>(hc, 128, nullptr, wt_cq1, cq_b1, cq, nullptr, 128, 128);
    k_loss<<<NC / 2, 256, 0, stream>>>(edge_lit, cptr, vq, cq, cmA);
    for (int ch = 0; ch < NC / CMCHUNK; ++ch) {
      size_t ro = (size_t)ch * CMCHUNK;
      mgemm<false, true, 1><<<dim3(CMCHUNK / 128, 2), 256, 0, stream>>>(cmA + ro * 384, 384, nullptr, wt_cm0, cm_b0, cmh, nullptr, 256, 384);
      mgemm<false, false, 2><<<dim3(CMCHUNK / 128, 2), 256, 0, stream>>>(cmh, 256, nullptr, wt_cm1, cm_b1, cd0 + ro * 128, cd1 + ro * 128, 128, 256);
    }
    k_gather<<<NV, 256, 0, stream>>>(lptr, lclause, cmA, cd0, gl, ugA, dw);
    k_vgrad<<<NV * 128 / 256, 256, 0, stream>>>(vq, gl, vdw, ugA);
    hipMemsetAsync(stats, 0, 132 * 4, stream);
    k_pn_stats<bf16><<<256, 256, 0, stream>>>(cd1, NC, stats);
    k_pn_final<<<1, 128, 0, stream>>>(stats, (float)NC);
    k_pn_apply_c<<<NC * 128 / 256, 256, 0, stream>>>(cd1, stats, cmA);
    mgemm<false, true, 1><<<dim3(NC / 128, 1), 256, 0, stream>>>(cmA, 384, nullptr, wt_co0, co_b0, lh, nullptr, 128, 128);
    k_logits<<<NC / 4, 256, 0, stream>>>(lh, co_w1, co_b1, out, t);
    mgemm<false, true, 1><<<dim3(NV / 128, 2), 256, 0, stream>>>(ugA, 512, nullptr, wt_ug0, ug_b0, uh1, nullptr, 256, 512);
    mgemm<false, true, 1><<<dim3(NV / 128, 2), 256, 0, stream>>>(uh1, 256, nullptr, wt_ug1, ug_b1, uh2, nullptr, 256, 256);
    mgemm<false, false, 0><<<dim3(NV / 128, 1), 256, 0, stream>>>(uh2, 256, nullptr, wt_ug2, ug_b2, uout, nullptr, 128, 256);
    hipMemsetAsync(stats, 0, 132 * 4, stream);
    k_pn_stats<float><<<256, 256, 0, stream>>>(uout, NV, stats);
    k_pn_final<<<1, 128, 0, stream>>>(stats, (float)NV);
    k_pn_apply_v<<<NV * 128 / 256, 256, 0, stream>>>(uout, stats, variables, ugA);
  }
}

// Round 5
// 1988.218 us; speedup vs baseline: 3.1969x; 1.0583x over previous
//
#include <hip/hip_runtime.h>
#include <math.h>

#define NV 24576
#define NC 98304
#define NE 294912
#define CMCHUNK 24576  // 4 chunks over NC

typedef unsigned short bf16;
typedef _Float16 f16;
using bf8 = __attribute__((ext_vector_type(8))) short;
using f4  = __attribute__((ext_vector_type(4))) float;

static constexpr float INV_CQM = 1.0f / 12582912.0f;  // 1/(NC*128)
static constexpr float LOG2E = 1.44269504f;
static constexpr float LN2 = 0.69314718f;

__device__ __forceinline__ float b2f(bf16 h) { return __uint_as_float(((unsigned)h) << 16); }
__device__ __forceinline__ bf16 f2b(float f) {
  unsigned u = __float_as_uint(f);
  u += 0x7fff + ((u >> 16) & 1);  // RNE
  return (bf16)(u >> 16);
}
// fast transcendentals: v_exp_f32 = 2^x, v_log_f32 = log2(x), v_rcp_f32 ~1ulp
__device__ __forceinline__ float fexp2(float x) { float r; asm("v_exp_f32 %0, %1" : "=v"(r) : "v"(x)); return r; }
__device__ __forceinline__ float flog2(float x) { float r; asm("v_log_f32 %0, %1" : "=v"(r) : "v"(x)); return r; }
__device__ __forceinline__ float frcpf(float x) { float r; asm("v_rcp_f32 %0, %1" : "=v"(r) : "v"(x)); return r; }
__device__ __forceinline__ float fsigm(float x) { return frcpf(1.0f + fexp2(-x * LOG2E)); }
__device__ __forceinline__ float fsoftplus(float x) {
  return fmaxf(x, 0.0f) + LN2 * flog2(1.0f + fexp2(-fabsf(x) * LOG2E));
}
__device__ __forceinline__ float cvt_ld(float x) { return x; }
__device__ __forceinline__ float cvt_ld(bf16 x) { return b2f(x); }

// direct global->LDS 16B DMA (lds dest: wave-uniform base + lane*16)
__device__ __forceinline__ void gload16(const void* g, void* l) {
  __builtin_amdgcn_global_load_lds((const __attribute__((address_space(1))) unsigned int*)g,
                                   (__attribute__((address_space(3))) unsigned int*)l, 16, 0, 0);
}

// ---------------- precompute kernels ----------------

__global__ __launch_bounds__(256) void k_cptr(const int* __restrict__ ec, int* __restrict__ ptr) {
  int c = blockIdx.x * 256 + threadIdx.x;
  if (c > NC) return;
  int lo = 0, hi = NE;
  while (lo < hi) { int mid = (lo + hi) >> 1; if (ec[mid] < c) lo = mid + 1; else hi = mid; }
  ptr[c] = lo;
}

__global__ __launch_bounds__(256) void k_litcnt(const int* __restrict__ el, int* __restrict__ cnt) {
  int e = blockIdx.x * 256 + threadIdx.x;
  atomicAdd(&cnt[el[e]], 1);
}

__global__ __launch_bounds__(1024) void k_scan(int* __restrict__ cnt, int* __restrict__ ptr) {
  __shared__ int wsum[16];
  __shared__ int carry_s;
  int tid = threadIdx.x, lane = tid & 63, w = tid >> 6;
  if (tid == 0) carry_s = 0;
  __syncthreads();
  for (int base = 0; base < 2 * NV; base += 1024) {
    int x = cnt[base + tid];
    int v = x;
#pragma unroll
    for (int off = 1; off < 64; off <<= 1) {
      int y = __shfl_up(v, off, 64);
      if (lane >= off) v += y;
    }
    if (lane == 63) wsum[w] = v;
    __syncthreads();
    int carry = carry_s;
    int wpre = 0;
    for (int i = 0; i < w; ++i) wpre += wsum[i];
    int excl = carry + wpre + (v - x);
    ptr[base + tid] = excl;
    cnt[base + tid] = excl;
    __syncthreads();
    if (tid == 1023) carry_s = carry + wpre + v;
  }
  __syncthreads();
  if (tid == 0) ptr[2 * NV] = carry_s;
}

__global__ __launch_bounds__(256) void k_fillsort(const int* __restrict__ el, const int* __restrict__ ec,
                                                  int* __restrict__ cur, int* __restrict__ lclause) {
  int e = blockIdx.x * 256 + threadIdx.x;
  int pos = atomicAdd(&cur[el[e]], 1);
  lclause[pos] = ec[e];
}

__global__ __launch_bounds__(256) void k_degree(const int* __restrict__ lptr, float* __restrict__ dw,
                                                float* __restrict__ vdw) {
  int l = blockIdx.x * 256 + threadIdx.x;
  if (l < 2 * NV) dw[l] = rsqrtf(fmaxf((float)(lptr[l + 1] - lptr[l]), 1.0f));
  if (l < NV) {
    int d = (lptr[l + 1] - lptr[l]) + (lptr[l + NV + 1] - lptr[l + NV]);
    vdw[l] = 4.0f * rsqrtf(fmaxf((float)d, 1.0f));
  }
}

__global__ __launch_bounds__(256) void k_init_v(float* __restrict__ variables, bf16* __restrict__ ugA) {
  int i = blockIdx.x * 256 + threadIdx.x;
  variables[i] = 1.0f;
  ugA[(size_t)(i >> 7) * 512 + 128 + (i & 127)] = 0x3F80;
}
__global__ __launch_bounds__(256) void k_init_c(bf16* __restrict__ cmA) {
  int i = blockIdx.x * 256 + threadIdx.x;
  cmA[(size_t)(i >> 7) * 384 + (i & 127)] = 0x3F80;
}

// transpose + bf16 convert weights: wt[n*Kpad+k] = w[k*N+n] (zero-pad k>=K)
__global__ __launch_bounds__(256) void k_wt(const float* __restrict__ w, bf16* __restrict__ wt,
                                            int K, int N, int Kpad) {
  int idx = blockIdx.x * 256 + threadIdx.x;
  int n = idx / Kpad, k = idx % Kpad;
  if (n >= N) return;
  wt[idx] = (k < K) ? f2b(w[(size_t)k * N + n]) : (bf16)0;
}

// ---------------- MFMA GEMM: 128x128 tile, 4 waves, BK=64, 2-phase double-buffered ----------------
// LDS linear dest via global_load_lds; XOR swizzle on GLOBAL source byte offset (involution),
// identical swizzle on the LDS read path. Prefetch next K-tile into other buffer while computing;
// counted s_waitcnt vmcnt(N) (never 0 mid-loop) + raw s_barrier + sched_barrier fences.
// A: bf16 row-major (lda elts). CONCAT: cols [0,128) from A0, [128,132) noise f32, rest 0.
// WT: bf16 N x KDIM row-major. OUT: 0=f32, 1=bf16, 2=dual bf16 split at col128, 3=softplus pair f16.

template <int KDIM, bool CONCAT, bool RELU, int OUT>
__global__ __launch_bounds__(256) void mgemm(const bf16* __restrict__ A0, int lda,
                                             const float* __restrict__ noise,
                                             const bf16* __restrict__ WT,
                                             const float* __restrict__ Bv,
                                             void* out0, void* out1, int ldOut) {
  __shared__ __align__(16) char smem[65536];
  constexpr int NT = KDIM / 64;
  const int tid = threadIdx.x;
  const int m0 = blockIdx.x * 128;
  const int n0 = blockIdx.y * 128;
  const int lane = tid & 63;
  const int w = tid >> 6;
  const int wr = w >> 1, wc = w & 1;
  const int rl = (tid >> 3) & 7;  // row within wave's 8-row staging group
  const int cc = tid & 7;         // 16B chunk
  const int swzoff = (cc * 16) ^ (rl << 4);

  auto stage = [&](int t, int buf) {
    char* As = smem + buf * 32768;
    char* Bs = As + 16384;
    const int k0 = t * 64;
    if (!CONCAT || k0 < 128) {
#pragma unroll
      for (int it = 0; it < 4; ++it) {
        int row0 = it * 32 + w * 8;  // wave-uniform
        int row = row0 + rl;         // row&7 == rl
        gload16((const char*)(A0 + (size_t)(m0 + row) * lda + k0) + swzoff, As + row0 * 128);
        gload16((const char*)(WT + (size_t)(n0 + row) * KDIM + k0) + swzoff, Bs + row0 * 128);
      }
    } else {  // noise columns: reg-stage A (swizzled ds_write), gload B (4 loads)
      const int srow = tid >> 3, schunk = tid & 7;
#pragma unroll
      for (int it = 0; it < 4; ++it) {
        int row = srow + it * 32;
        alignas(16) bf16 tmp[8];
#pragma unroll
        for (int e = 0; e < 8; ++e) {
          int kk = schunk * 8 + e;
          tmp[e] = (kk < 4) ? f2b(noise[(size_t)(m0 + row) * 4 + kk]) : (bf16)0;
        }
        *reinterpret_cast<uint4*>(&As[row * 128 + ((schunk * 16) ^ ((row & 7) << 4))]) =
            *reinterpret_cast<uint4*>(tmp);
        int row0 = it * 32 + w * 8;
        gload16((const char*)(WT + (size_t)(n0 + row0 + rl) * KDIM + k0) + swzoff, Bs + row0 * 128);
      }
    }
  };

  f4 acc[4][4] = {};
  stage(0, 0);
#pragma unroll
  for (int t = 0; t < NT; ++t) {
    const int buf = t & 1;
    __builtin_amdgcn_sched_barrier(0);
    if (t + 1 < NT) {
      stage(t + 1, buf ^ 1);  // prefetch next tile into other buffer (stays in flight)
      if (CONCAT && (t + 1) * 64 >= 128) {
        asm volatile("s_waitcnt vmcnt(4) lgkmcnt(0)" ::: "memory");
      } else {
        asm volatile("s_waitcnt vmcnt(8) lgkmcnt(0)" ::: "memory");
      }
    } else {
      asm volatile("s_waitcnt vmcnt(0) lgkmcnt(0)" ::: "memory");
    }
    __builtin_amdgcn_s_barrier();
    __builtin_amdgcn_sched_barrier(0);
    const char* As = smem + buf * 32768;
    const char* Bs = As + 16384;
#pragma unroll
    for (int kk = 0; kk < 2; ++kk) {
      bf8 a[4], b[4];
#pragma unroll
      for (int i = 0; i < 4; ++i) {
        int r = wr * 64 + i * 16 + (lane & 15);
        int cby = (kk * 64 + ((lane >> 4) * 16)) ^ ((r & 7) << 4);
        a[i] = *reinterpret_cast<const bf8*>(&As[r * 128 + cby]);
        int c = wc * 64 + i * 16 + (lane & 15);
        int cby2 = (kk * 64 + ((lane >> 4) * 16)) ^ ((c & 7) << 4);
        b[i] = *reinterpret_cast<const bf8*>(&Bs[c * 128 + cby2]);
      }
#pragma unroll
      for (int i = 0; i < 4; ++i)
#pragma unroll
        for (int j = 0; j < 4; ++j)
          acc[i][j] = __builtin_amdgcn_mfma_f32_16x16x32_bf16(a[i], b[j], acc[i][j], 0, 0, 0);
    }
    __builtin_amdgcn_sched_barrier(0);
    __builtin_amdgcn_s_barrier();  // all waves done reading buf -> next iter may stage into it
  }
  const int colloc = wc * 64 + (lane & 15);
  const int rowbase = m0 + wr * 64 + ((lane >> 4) << 2);
#pragma unroll
  for (int j = 0; j < 4; ++j) {
    int c = n0 + colloc + j * 16;
    float bias = Bv[c];
#pragma unroll
    for (int i = 0; i < 4; ++i) {
      int rb = rowbase + i * 16;
#pragma unroll
      for (int p = 0; p < 4; ++p) {
        float v = acc[i][j][p] + bias;
        if (RELU) v = fmaxf(v, 0.0f);
        int r = rb + p;
        if constexpr (OUT == 0) {
          ((float*)out0)[(size_t)r * ldOut + c] = v;
        } else if constexpr (OUT == 1) {
          ((bf16*)out0)[(size_t)r * ldOut + c] = f2b(v);
        } else if constexpr (OUT == 2) {
          bf16* o = (c < 128) ? (bf16*)out0 : (bf16*)out1;
          o[(size_t)r * 128 + (c & 127)] = f2b(v);
        } else {  // OUT==3: softplus(+v), softplus(-v) as f16 (vq path)
          float tq = LN2 * flog2(1.0f + fexp2(-fabsf(v) * LOG2E));
          ((f16*)out0)[(size_t)r * 128 + c] = (f16)(fmaxf(v, 0.0f) + tq);
          ((f16*)out1)[(size_t)r * 128 + c] = (f16)(fmaxf(-v, 0.0f) + tq);
        }
      }
    }
  }
}

// ---------------- graph / elementwise kernels ----------------

// per clause: csum = sum of precomputed softplus; loss4/cg -> cmA cols 128..384
__global__ __launch_bounds__(256) void k_loss(const int* __restrict__ edge_lit, const int* __restrict__ cptr,
                                              const f16* __restrict__ spp, const f16* __restrict__ spn,
                                              const bf16* __restrict__ cq, bf16* __restrict__ cmA) {
  int c = blockIdx.x * 2 + (threadIdx.x >> 7);
  int q = threadIdx.x & 127;
  int e0 = cptr[c], e1 = cptr[c + 1];
  float csum = 0.0f;
  for (int e = e0; e < e1; ++e) {
    int lit = edge_lit[e];
    const f16* base = (lit < NV) ? (spp + (size_t)lit * 128) : (spn + (size_t)(lit - NV) * 128);
    csum += (float)base[q];
  }
  float s = fsigm(b2f(cq[(size_t)c * 128 + q]));
  float L = fexp2(-csum * LOG2E) * s;
  cmA[(size_t)c * 384 + 128 + q] = f2b(4.0f * L);
  cmA[(size_t)c * 384 + 256 + q] = f2b(L * (1.0f - s) * INV_CQM);
}

// per variable (both literals in one block): gathers + vgrad. sigm(vq) = exp2(-log2e*sp_neg).
__global__ __launch_bounds__(256) void k_gatherv(const int* __restrict__ lptr, const int* __restrict__ lclause,
                                                 const bf16* __restrict__ cmA, const bf16* __restrict__ cd0,
                                                 const f16* __restrict__ spn, const float* __restrict__ dw,
                                                 const float* __restrict__ vdw, bf16* __restrict__ ugA) {
  int v = blockIdx.x;
  int half = threadIdx.x >> 7, q = threadIdx.x & 127;
  int l = v + half * NV;
  int j0 = lptr[l], j1 = lptr[l + 1];
  float sg = 0.0f, sv = 0.0f;
  for (int j = j0; j < j1; ++j) {
    int c = lclause[j];
    sg += b2f(cmA[(size_t)c * 384 + 128 + q]);
    sv += b2f(cd0[(size_t)c * 128 + q]);
  }
  __shared__ float sgl[2][128];
  sgl[half][q] = sg;
  ugA[(size_t)v * 512 + 256 + half * 128 + q] = f2b(sv * dw[l]);
  __syncthreads();
  if (half == 0) {
    float s = fexp2(-LOG2E * (float)spn[(size_t)v * 128 + q]);
    float g = ((1.0f - s) * sgl[1][q] - s * sgl[0][q]) * (INV_CQM * 0.25f) * vdw[v];
    ugA[(size_t)v * 512 + q] = f2b(g);
  }
}

template <typename T>
__global__ __launch_bounds__(256) void k_pn_stats(const T* __restrict__ X, int R, float* __restrict__ stats) {
  int q = threadIdx.x & 127;
  int rg = threadIdx.x >> 7;
  float cs = 0.0f, ss = 0.0f;
  for (int r = blockIdx.x * 2 + rg; r < R; r += gridDim.x * 2) {
    float x = cvt_ld(X[(size_t)r * 128 + q]);
    cs += x;
    ss += x * x;
  }
  __shared__ float scs[256], sss[256];
  scs[threadIdx.x] = cs;
  sss[threadIdx.x] = ss;
  __syncthreads();
  if (threadIdx.x < 128) atomicAdd(&stats[q], scs[q] + scs[128 + q]);
  for (int off = 128; off; off >>= 1) {
    if (threadIdx.x < off) sss[threadIdx.x] += sss[threadIdx.x + off];
    __syncthreads();
  }
  if (threadIdx.x == 0) atomicAdd(&stats[128], sss[0]);
}

__global__ __launch_bounds__(128) void k_pn_final(float* __restrict__ stats, float R) {
  __shared__ float s[128];
  int q = threadIdx.x;
  float m = stats[q] / R;
  s[q] = m * m;
  __syncthreads();
  for (int off = 64; off; off >>= 1) {
    if (q < off) s[q] += s[q + off];
    __syncthreads();
  }
  if (q == 0) {
    float var = (stats[128] - R * s[0]) / (R * 128.0f);
    stats[129] = rsqrtf(fmaxf(var, 0.0f) + 1e-6f) * 0.25f;
  }
  stats[q] = m;
}

__global__ __launch_bounds__(256) void k_pn_apply_c(const bf16* __restrict__ cd1, const float* __restrict__ stats,
                                                    bf16* __restrict__ cmA) {
  int i = blockIdx.x * 256 + threadIdx.x;
  int c = i >> 7, q = i & 127;
  float x = b2f(cd1[i]);
  float old = b2f(cmA[(size_t)c * 384 + q]);
  cmA[(size_t)c * 384 + q] = f2b((x - stats[q]) * stats[129] + 0.1f * old);
}

__global__ __launch_bounds__(256) void k_pn_apply_v(const float* __restrict__ uout, const float* __restrict__ stats,
                                                    float* __restrict__ variables, bf16* __restrict__ ugA) {
  int i = blockIdx.x * 256 + threadIdx.x;
  int v = i >> 7, q = i & 127;
  float nv = (uout[i] - stats[q]) * stats[129] + 0.1f * variables[i];
  variables[i] = nv;
  ugA[(size_t)v * 512 + 128 + q] = f2b(nv);
}

__global__ __launch_bounds__(256) void k_logits(const bf16* __restrict__ lh, const float* __restrict__ w1,
                                                const float* __restrict__ b1, float* __restrict__ outp, int t) {
  int wv = threadIdx.x >> 6, lane = threadIdx.x & 63;
  int c = blockIdx.x * 4 + wv;
  const bf16* row = lh + (size_t)c * 128;
  float v = b2f(row[lane]) * w1[lane] + b2f(row[64 + lane]) * w1[64 + lane];
#pragma unroll
  for (int off = 32; off; off >>= 1) v += __shfl_down(v, off, 64);
  if (lane == 0) {
    float lg = v + b1[0];
    outp[(size_t)t * NC + c] = fsigm(lg);
    outp[(size_t)4 * NC + (size_t)t * NC + c] = fsoftplus(lg);
  }
}

// ---------------- host ----------------

extern "C" void kernel_launch(void* const* d_in, const int* in_sizes, int n_in,
                              void* d_out, int out_size, void* d_ws, size_t ws_size,
                              hipStream_t stream) {
  const int* edge_lit = (const int*)d_in[0];
  const int* edge_clause = (const int*)d_in[1];
  const float* noise_v = (const float*)d_in[2];
  const float* noise_c = (const float*)d_in[3];
  const float* vq_w0 = (const float*)d_in[4];  const float* vq_b0 = (const float*)d_in[5];
  const float* vq_w1 = (const float*)d_in[6];  const float* vq_b1 = (const float*)d_in[7];
  const float* cq_w0 = (const float*)d_in[8];  const float* cq_b0 = (const float*)d_in[9];
  const float* cq_w1 = (const float*)d_in[10]; const float* cq_b1 = (const float*)d_in[11];
  const float* cm_w0 = (const float*)d_in[12]; const float* cm_b0 = (const float*)d_in[13];
  const float* cm_w1 = (const float*)d_in[14]; const float* cm_b1 = (const float*)d_in[15];
  const float* ug_w0 = (const float*)d_in[16]; const float* ug_b0 = (const float*)d_in[17];
  const float* ug_w1 = (const float*)d_in[18]; const float* ug_b1 = (const float*)d_in[19];
  const float* ug_w2 = (const float*)d_in[20]; const float* ug_b2 = (const float*)d_in[21];
  const float* co_w0 = (const float*)d_in[22]; const float* co_b0 = (const float*)d_in[23];
  const float* co_w1 = (const float*)d_in[24]; const float* co_b1 = (const float*)d_in[25];
  float* out = (float*)d_out;

  char* base = (char*)d_ws;
  size_t off = 0;
  auto A = [&](size_t n) -> char* {
    char* p = base + off;
    off = (off + n + 255) & ~(size_t)255;
    return p;
  };
  float* variables = (float*)A((size_t)NV * 128 * 4);
  bf16* cmA        = (bf16*)A((size_t)NC * 384 * 2);    // [clauses_h | loss4 | cg]
  bf16* ugA        = (bf16*)A((size_t)NV * 512 * 2);    // [vgrad | vars_h | vl_lo*dw | vl_hi*dw]
  char* R_cq       = A((size_t)NC * 128 * 2);           // cq | cd0 | lh
  char* R_h        = A((size_t)NC * 128 * 2);           // hv/hc | cd1 | uh1+uh2
  char* R_big      = A((size_t)2 * NV * 128 * 2 + (size_t)NV * 128 * 4);  // cmh | spp+spn -> uout
  bf16* wtb        = (bf16*)A(983424);
  int* cptr = (int*)A((size_t)(NC + 1) * 4);
  int* lptr = (int*)A((size_t)(2 * NV + 1) * 4);
  int* lcur = (int*)A((size_t)2 * NV * 4);
  int* lclause = (int*)A((size_t)NE * 4);
  float* dw  = (float*)A((size_t)2 * NV * 4);
  float* vdw = (float*)A((size_t)NV * 4);
  float* stats = (float*)A(2048);
  if (off > ws_size) {
    hipMemsetAsync(d_out, 0xFF, (size_t)out_size * 4, stream);
    return;
  }

  bf16* cq  = (bf16*)R_cq;
  bf16* cd0 = (bf16*)R_cq;
  bf16* lh  = (bf16*)R_cq;
  bf16* hv  = (bf16*)R_h;
  bf16* hc  = (bf16*)R_h;
  bf16* cd1 = (bf16*)R_h;
  bf16* uh1 = (bf16*)R_h;
  bf16* uh2 = (bf16*)(R_h + (size_t)NV * 256 * 2);
  bf16* cmh = (bf16*)R_big;
  f16* spp  = (f16*)(R_big + 12582912);           // lives [vq1 .. k_gatherv]
  f16* spn  = spp + (size_t)NV * 128;
  float* uout = (float*)(R_big + 12582912);       // written after spp/spn dead

  size_t wo = 0;
  auto WTa = [&](int n, int kp) { bf16* p = wtb + wo; wo += (size_t)n * kp; return p; };
  bf16* wt_vq0 = WTa(128, 192); bf16* wt_vq1 = WTa(128, 128);
  bf16* wt_cq0 = WTa(128, 192); bf16* wt_cq1 = WTa(128, 128);
  bf16* wt_cm0 = WTa(256, 384); bf16* wt_cm1 = WTa(256, 256);
  bf16* wt_ug0 = WTa(256, 512); bf16* wt_ug1 = WTa(256, 256);
  bf16* wt_ug2 = WTa(128, 256); bf16* wt_co0 = WTa(128, 128);

  hipMemsetAsync(lcur, 0, (size_t)2 * NV * 4, stream);
  k_cptr<<<(NC + 256) / 256, 256, 0, stream>>>(edge_clause, cptr);
  k_litcnt<<<NE / 256, 256, 0, stream>>>(edge_lit, lcur);
  k_scan<<<1, 1024, 0, stream>>>(lcur, lptr);
  k_fillsort<<<NE / 256, 256, 0, stream>>>(edge_lit, edge_clause, lcur, lclause);
  k_degree<<<(2 * NV + 255) / 256, 256, 0, stream>>>(lptr, dw, vdw);
  k_init_v<<<NV * 128 / 256, 256, 0, stream>>>(variables, ugA);
  k_init_c<<<NC * 128 / 256, 256, 0, stream>>>(cmA);
  k_wt<<<128 * 192 / 256, 256, 0, stream>>>(vq_w0, wt_vq0, 132, 128, 192);
  k_wt<<<128 * 128 / 256, 256, 0, stream>>>(vq_w1, wt_vq1, 128, 128, 128);
  k_wt<<<128 * 192 / 256, 256, 0, stream>>>(cq_w0, wt_cq0, 132, 128, 192);
  k_wt<<<128 * 128 / 256, 256, 0, stream>>>(cq_w1, wt_cq1, 128, 128, 128);
  k_wt<<<256 * 384 / 256, 256, 0, stream>>>(cm_w0, wt_cm0, 384, 256, 384);
  k_wt<<<256 * 256 / 256, 256, 0, stream>>>(cm_w1, wt_cm1, 256, 256, 256);
  k_wt<<<256 * 512 / 256, 256, 0, stream>>>(ug_w0, wt_ug0, 512, 256, 512);
  k_wt<<<256 * 256 / 256, 256, 0, stream>>>(ug_w1, wt_ug1, 256, 256, 256);
  k_wt<<<128 * 256 / 256, 256, 0, stream>>>(ug_w2, wt_ug2, 256, 128, 256);
  k_wt<<<128 * 128 / 256, 256, 0, stream>>>(co_w0, wt_co0, 128, 128, 128);

  for (int t = 0; t < 4; ++t) {
    const float* nvp = noise_v + (size_t)t * NV * 4;
    const float* ncp = noise_c + (size_t)t * NC * 4;
    // vq path: hv = relu([vars,nv]@W0+b0); softplus(+-(hv@W1+b1)) -> spp/spn (f16)
    mgemm<192, true, true, 1><<<dim3(NV / 128, 1), 256, 0, stream>>>(ugA + 128, 512, nvp, wt_vq0, vq_b0, hv, nullptr, 128);
    mgemm<128, false, false, 3><<<dim3(NV / 128, 1), 256, 0, stream>>>(hv, 128, nullptr, wt_vq1, vq_b1, spp, spn, 128);
    // cq path
    mgemm<192, true, true, 1><<<dim3(NC / 128, 1), 256, 0, stream>>>(cmA, 384, ncp, wt_cq0, cq_b0, hc, nullptr, 128);
    mgemm<128, false, false, 1><<<dim3(NC / 128, 1), 256, 0, stream>>>(hc, 128, nullptr, wt_cq1, cq_b1, cq, nullptr, 128);
    k_loss<<<NC / 2, 256, 0, stream>>>(edge_lit, cptr, spp, spn, cq, cmA);
    // clause_data = mlp2(cmA) — chunked
    for (int ch = 0; ch < NC / CMCHUNK; ++ch) {
      size_t ro = (size_t)ch * CMCHUNK;
      mgemm<384, false, true, 1><<<dim3(CMCHUNK / 128, 2), 256, 0, stream>>>(cmA + ro * 384, 384, nullptr, wt_cm0, cm_b0, cmh, nullptr, 256);
      mgemm<256, false, false, 2><<<dim3(CMCHUNK / 128, 2), 256, 0, stream>>>(cmh, 256, nullptr, wt_cm1, cm_b1, cd0 + ro * 128, cd1 + ro * 128, 128);
    }
    // merged gathers + vgrad (pair block per variable)
    k_gatherv<<<NV, 256, 0, stream>>>(lptr, lclause, cmA, cd0, spn, dw, vdw, ugA);
    // clauses = pair_norm(cd1)*0.25 + 0.1*clauses
    hipMemsetAsync(stats, 0, 132 * 4, stream);
    k_pn_stats<bf16><<<256, 256, 0, stream>>>(cd1, NC, stats);
    k_pn_final<<<1, 128, 0, stream>>>(stats, (float)NC);
    k_pn_apply_c<<<NC * 128 / 256, 256, 0, stream>>>(cd1, stats, cmA);
    // logits head
    mgemm<128, false, true, 1><<<dim3(NC / 128, 1), 256, 0, stream>>>(cmA, 384, nullptr, wt_co0, co_b0, lh, nullptr, 128);
    k_logits<<<NC / 4, 256, 0, stream>>>(lh, co_w1, co_b1, out, t);
    // variables = pair_norm(mlp3(ugA))*0.25 + 0.1*variables
    mgemm<512, false, true, 1><<<dim3(NV / 128, 2), 256, 0, stream>>>(ugA, 512, nullptr, wt_ug0, ug_b0, uh1, nullptr, 256);
    mgemm<256, false, true, 1><<<dim3(NV / 128, 2), 256, 0, stream>>>(uh1, 256, nullptr, wt_ug1, ug_b1, uh2, nullptr, 256);
    mgemm<256, false, false, 0><<<dim3(NV / 128, 1), 256, 0, stream>>>(uh2, 256, nullptr, wt_ug2, ug_b2, uout, nullptr, 128);
    hipMemsetAsync(stats, 0, 132 * 4, stream);
    k_pn_stats<float><<<256, 256, 0, stream>>>(uout, NV, stats);
    k_pn_final<<<1, 128, 0, stream>>>(stats, (float)NV);
    k_pn_apply_v<<<NV * 128 / 256, 256, 0, stream>>>(uout, stats, variables, ugA);
  }
}

// Round 6
// 1939.860 us; speedup vs baseline: 3.2766x; 1.0249x over previous
//
#include <hip/hip_runtime.h>
#include <math.h>

#define NV 24576
#define NC 98304
#define NE 294912
#define CMCHUNK 24576  // 4 chunks over NC

typedef unsigned short bf16;
typedef _Float16 f16;
using bf8 = __attribute__((ext_vector_type(8))) short;
using f4  = __attribute__((ext_vector_type(4))) float;

static constexpr float INV_CQM = 1.0f / 12582912.0f;  // 1/(NC*128)
static constexpr float LOG2E = 1.44269504f;
static constexpr float LN2 = 0.69314718f;

__device__ __forceinline__ float b2f(bf16 h) { return __uint_as_float(((unsigned)h) << 16); }
__device__ __forceinline__ bf16 f2b(float f) {
  unsigned u = __float_as_uint(f);
  u += 0x7fff + ((u >> 16) & 1);  // RNE
  return (bf16)(u >> 16);
}
// fast transcendentals: v_exp_f32 = 2^x, v_log_f32 = log2(x), v_rcp_f32 ~1ulp
__device__ __forceinline__ float fexp2(float x) { float r; asm("v_exp_f32 %0, %1" : "=v"(r) : "v"(x)); return r; }
__device__ __forceinline__ float flog2(float x) { float r; asm("v_log_f32 %0, %1" : "=v"(r) : "v"(x)); return r; }
__device__ __forceinline__ float frcpf(float x) { float r; asm("v_rcp_f32 %0, %1" : "=v"(r) : "v"(x)); return r; }
__device__ __forceinline__ float fsigm(float x) { return frcpf(1.0f + fexp2(-x * LOG2E)); }
__device__ __forceinline__ float fsoftplus(float x) {
  return fmaxf(x, 0.0f) + LN2 * flog2(1.0f + fexp2(-fabsf(x) * LOG2E));
}
__device__ __forceinline__ float cvt_ld(float x) { return x; }
__device__ __forceinline__ float cvt_ld(bf16 x) { return b2f(x); }

// direct global->LDS 16B DMA (lds dest: wave-uniform base + lane*16)
__device__ __forceinline__ void gload16(const void* g, void* l) {
  __builtin_amdgcn_global_load_lds((const __attribute__((address_space(1))) unsigned int*)g,
                                   (__attribute__((address_space(3))) unsigned int*)l, 16, 0, 0);
}

// ---------------- precompute kernels ----------------

__global__ __launch_bounds__(256) void k_cptr(const int* __restrict__ ec, int* __restrict__ ptr) {
  int c = blockIdx.x * 256 + threadIdx.x;
  if (c > NC) return;
  int lo = 0, hi = NE;
  while (lo < hi) { int mid = (lo + hi) >> 1; if (ec[mid] < c) lo = mid + 1; else hi = mid; }
  ptr[c] = lo;
}

__global__ __launch_bounds__(256) void k_litcnt(const int* __restrict__ el, int* __restrict__ cnt) {
  int e = blockIdx.x * 256 + threadIdx.x;
  atomicAdd(&cnt[el[e]], 1);
}

__global__ __launch_bounds__(1024) void k_scan(int* __restrict__ cnt, int* __restrict__ ptr) {
  __shared__ int wsum[16];
  __shared__ int carry_s;
  int tid = threadIdx.x, lane = tid & 63, w = tid >> 6;
  if (tid == 0) carry_s = 0;
  __syncthreads();
  for (int base = 0; base < 2 * NV; base += 1024) {
    int x = cnt[base + tid];
    int v = x;
#pragma unroll
    for (int off = 1; off < 64; off <<= 1) {
      int y = __shfl_up(v, off, 64);
      if (lane >= off) v += y;
    }
    if (lane == 63) wsum[w] = v;
    __syncthreads();
    int carry = carry_s;
    int wpre = 0;
    for (int i = 0; i < w; ++i) wpre += wsum[i];
    int excl = carry + wpre + (v - x);
    ptr[base + tid] = excl;
    cnt[base + tid] = excl;
    __syncthreads();
    if (tid == 1023) carry_s = carry + wpre + v;
  }
  __syncthreads();
  if (tid == 0) ptr[2 * NV] = carry_s;
}

__global__ __launch_bounds__(256) void k_fillsort(const int* __restrict__ el, const int* __restrict__ ec,
                                                  int* __restrict__ cur, int* __restrict__ lclause) {
  int e = blockIdx.x * 256 + threadIdx.x;
  int pos = atomicAdd(&cur[el[e]], 1);
  lclause[pos] = ec[e];
}

__global__ __launch_bounds__(256) void k_degree(const int* __restrict__ lptr, float* __restrict__ dw,
                                                float* __restrict__ vdw) {
  int l = blockIdx.x * 256 + threadIdx.x;
  if (l < 2 * NV) dw[l] = rsqrtf(fmaxf((float)(lptr[l + 1] - lptr[l]), 1.0f));
  if (l < NV) {
    int d = (lptr[l + 1] - lptr[l]) + (lptr[l + NV + 1] - lptr[l + NV]);
    vdw[l] = 4.0f * rsqrtf(fmaxf((float)d, 1.0f));
  }
}

__global__ __launch_bounds__(256) void k_init_v(float* __restrict__ variables, bf16* __restrict__ ugA) {
  int i = blockIdx.x * 256 + threadIdx.x;
  variables[i] = 1.0f;
  ugA[(size_t)(i >> 7) * 512 + 128 + (i & 127)] = 0x3F80;
}
__global__ __launch_bounds__(256) void k_init_c(bf16* __restrict__ cmA) {
  int i = blockIdx.x * 256 + threadIdx.x;
  cmA[(size_t)(i >> 7) * 384 + (i & 127)] = 0x3F80;
}

// transpose + bf16 convert weights: wt[n*Kpad+k] = w[k*N+n] (zero-pad k>=K)
__global__ __launch_bounds__(256) void k_wt(const float* __restrict__ w, bf16* __restrict__ wt,
                                            int K, int N, int Kpad) {
  int idx = blockIdx.x * 256 + threadIdx.x;
  int n = idx / Kpad, k = idx % Kpad;
  if (n >= N) return;
  wt[idx] = (k < K) ? f2b(w[(size_t)k * N + n]) : (bf16)0;
}

// ---------------- MFMA GEMM: 128x128 tile, 4 waves, BK=64, 2-phase double-buffered ----------------
// LDS linear dest via global_load_lds; XOR swizzle on GLOBAL source byte offset (involution),
// identical swizzle on the LDS read path. Prefetch next K-tile into other buffer while computing;
// counted s_waitcnt vmcnt(N) (never 0 mid-loop) + raw s_barrier + sched_barrier fences.
// A: bf16 row-major (lda elts). CONCAT: cols [0,128) from A0, [128,132) noise f32, rest 0.
// WT: bf16 N x KDIM row-major.
// OUT: 0=f32, 1=bf16, 2=dual bf16 split at col128, 3=softplus pair f16,
//      4=logits head fused: out0=final out (f32), out1=w1 (f32[128]), noise[0]=b1, ldOut=t.

template <int KDIM, bool CONCAT, bool RELU, int OUT>
__global__ __launch_bounds__(256) void mgemm(const bf16* __restrict__ A0, int lda,
                                             const float* __restrict__ noise,
                                             const bf16* __restrict__ WT,
                                             const float* __restrict__ Bv,
                                             void* out0, void* out1, int ldOut) {
  __shared__ __align__(16) char smem[65536];
  constexpr int NT = KDIM / 64;
  const int tid = threadIdx.x;
  const int m0 = blockIdx.x * 128;
  const int n0 = blockIdx.y * 128;
  const int lane = tid & 63;
  const int w = tid >> 6;
  const int wr = w >> 1, wc = w & 1;
  const int rl = (tid >> 3) & 7;  // row within wave's 8-row staging group
  const int cc = tid & 7;         // 16B chunk
  const int swzoff = (cc * 16) ^ (rl << 4);

  auto stage = [&](int t, int buf) {
    char* As = smem + buf * 32768;
    char* Bs = As + 16384;
    const int k0 = t * 64;
    if (!CONCAT || k0 < 128) {
#pragma unroll
      for (int it = 0; it < 4; ++it) {
        int row0 = it * 32 + w * 8;  // wave-uniform
        int row = row0 + rl;         // row&7 == rl
        gload16((const char*)(A0 + (size_t)(m0 + row) * lda + k0) + swzoff, As + row0 * 128);
        gload16((const char*)(WT + (size_t)(n0 + row) * KDIM + k0) + swzoff, Bs + row0 * 128);
      }
    } else {  // noise columns: reg-stage A (swizzled ds_write), gload B (4 loads)
      const int srow = tid >> 3, schunk = tid & 7;
#pragma unroll
      for (int it = 0; it < 4; ++it) {
        int row = srow + it * 32;
        alignas(16) bf16 tmp[8];
#pragma unroll
        for (int e = 0; e < 8; ++e) {
          int kk = schunk * 8 + e;
          tmp[e] = (kk < 4) ? f2b(noise[(size_t)(m0 + row) * 4 + kk]) : (bf16)0;
        }
        *reinterpret_cast<uint4*>(&As[row * 128 + ((schunk * 16) ^ ((row & 7) << 4))]) =
            *reinterpret_cast<uint4*>(tmp);
        int row0 = it * 32 + w * 8;
        gload16((const char*)(WT + (size_t)(n0 + row0 + rl) * KDIM + k0) + swzoff, Bs + row0 * 128);
      }
    }
  };

  f4 acc[4][4] = {};
  stage(0, 0);
#pragma unroll
  for (int t = 0; t < NT; ++t) {
    const int buf = t & 1;
    __builtin_amdgcn_sched_barrier(0);
    if (t + 1 < NT) {
      stage(t + 1, buf ^ 1);  // prefetch next tile into other buffer (stays in flight)
      if (CONCAT && (t + 1) * 64 >= 128) {
        asm volatile("s_waitcnt vmcnt(4) lgkmcnt(0)" ::: "memory");
      } else {
        asm volatile("s_waitcnt vmcnt(8) lgkmcnt(0)" ::: "memory");
      }
    } else {
      asm volatile("s_waitcnt vmcnt(0) lgkmcnt(0)" ::: "memory");
    }
    __builtin_amdgcn_s_barrier();
    __builtin_amdgcn_sched_barrier(0);
    const char* As = smem + buf * 32768;
    const char* Bs = As + 16384;
#pragma unroll
    for (int kk = 0; kk < 2; ++kk) {
      bf8 a[4], b[4];
#pragma unroll
      for (int i = 0; i < 4; ++i) {
        int r = wr * 64 + i * 16 + (lane & 15);
        int cby = (kk * 64 + ((lane >> 4) * 16)) ^ ((r & 7) << 4);
        a[i] = *reinterpret_cast<const bf8*>(&As[r * 128 + cby]);
        int c = wc * 64 + i * 16 + (lane & 15);
        int cby2 = (kk * 64 + ((lane >> 4) * 16)) ^ ((c & 7) << 4);
        b[i] = *reinterpret_cast<const bf8*>(&Bs[c * 128 + cby2]);
      }
#pragma unroll
      for (int i = 0; i < 4; ++i)
#pragma unroll
        for (int j = 0; j < 4; ++j)
          acc[i][j] = __builtin_amdgcn_mfma_f32_16x16x32_bf16(a[i], b[j], acc[i][j], 0, 0, 0);
    }
    __builtin_amdgcn_sched_barrier(0);
    __builtin_amdgcn_s_barrier();  // all waves done reading buf -> next iter may stage into it
  }
  const int colloc = wc * 64 + (lane & 15);
  const int rowbase = m0 + wr * 64 + ((lane >> 4) << 2);

  if constexpr (OUT == 4) {
    // fused logits head: logit[r] = sum_c relu(h[r][c]+Bv[c]) * w1[c] + b1
    const float* w1 = (const float*)out1;
    float* outp = (float*)out0;
    const int t = ldOut;
    float part[4][4];
#pragma unroll
    for (int i = 0; i < 4; ++i)
#pragma unroll
      for (int p = 0; p < 4; ++p) part[i][p] = 0.0f;
#pragma unroll
    for (int j = 0; j < 4; ++j) {
      int c = colloc + j * 16;  // n0 == 0 for this kernel (N=128)
      float bias = Bv[c];
      float w1c = w1[c];
#pragma unroll
      for (int i = 0; i < 4; ++i)
#pragma unroll
        for (int p = 0; p < 4; ++p)
          part[i][p] += fmaxf(acc[i][j][p] + bias, 0.0f) * w1c;
    }
#pragma unroll
    for (int m = 1; m < 16; m <<= 1)
#pragma unroll
      for (int i = 0; i < 4; ++i)
#pragma unroll
        for (int p = 0; p < 4; ++p)
          part[i][p] += __shfl_xor(part[i][p], m, 64);
    float* red = (float*)smem;  // [2][128]; safe: last loop iter ended with s_barrier
    if ((lane & 15) == 0) {
#pragma unroll
      for (int i = 0; i < 4; ++i)
#pragma unroll
        for (int p = 0; p < 4; ++p)
          red[wc * 128 + wr * 64 + i * 16 + ((lane >> 4) << 2) + p] = part[i][p];
    }
    __syncthreads();
    if (tid < 128) {
      float lg = red[tid] + red[128 + tid] + noise[0];
      int row = m0 + tid;
      outp[(size_t)t * NC + row] = fsigm(lg);
      outp[(size_t)4 * NC + (size_t)t * NC + row] = fsoftplus(lg);
    }
    return;
  }

#pragma unroll
  for (int j = 0; j < 4; ++j) {
    int c = n0 + colloc + j * 16;
    float bias = Bv[c];
#pragma unroll
    for (int i = 0; i < 4; ++i) {
      int rb = rowbase + i * 16;
#pragma unroll
      for (int p = 0; p < 4; ++p) {
        float v = acc[i][j][p] + bias;
        if (RELU) v = fmaxf(v, 0.0f);
        int r = rb + p;
        if constexpr (OUT == 0) {
          ((float*)out0)[(size_t)r * ldOut + c] = v;
        } else if constexpr (OUT == 1) {
          ((bf16*)out0)[(size_t)r * ldOut + c] = f2b(v);
        } else if constexpr (OUT == 2) {
          bf16* o = (c < 128) ? (bf16*)out0 : (bf16*)out1;
          o[(size_t)r * 128 + (c & 127)] = f2b(v);
        } else {  // OUT==3: softplus(+v), softplus(-v) as f16 (vq path)
          float tq = LN2 * flog2(1.0f + fexp2(-fabsf(v) * LOG2E));
          ((f16*)out0)[(size_t)r * 128 + c] = (f16)(fmaxf(v, 0.0f) + tq);
          ((f16*)out1)[(size_t)r * 128 + c] = (f16)(fmaxf(-v, 0.0f) + tq);
        }
      }
    }
  }
}

// ---------------- graph / elementwise kernels ----------------

// per clause: csum = sum of precomputed softplus (sp has 2NV rows: [0,NV)=+, [NV,2NV)=-).
// 16 clauses/block (8 per q-group), edge loop unrolled x4 for memory-level parallelism.
__global__ __launch_bounds__(256) void k_loss(const int* __restrict__ edge_lit, const int* __restrict__ cptr,
                                              const f16* __restrict__ sp, const bf16* __restrict__ cq,
                                              bf16* __restrict__ cmA) {
  const int g = threadIdx.x >> 7;
  const int q = threadIdx.x & 127;
  const int c0 = blockIdx.x * 16 + g * 8;
#pragma unroll
  for (int ci = 0; ci < 8; ++ci) {
    int c = c0 + ci;
    int e0 = cptr[c], e1 = cptr[c + 1];
    float csum = 0.0f;
    for (int e = e0; e < e1; e += 4) {
#pragma unroll
      for (int k = 0; k < 4; ++k) {
        int ee = e + k;
        bool ok = ee < e1;
        int lit = ok ? edge_lit[ee] : 0;
        float v = ok ? (float)sp[(size_t)lit * 128 + q] : 0.0f;
        csum += v;
      }
    }
    float s = fsigm(b2f(cq[(size_t)c * 128 + q]));
    float L = fexp2(-csum * LOG2E) * s;
    cmA[(size_t)c * 384 + 128 + q] = f2b(4.0f * L);
    cmA[(size_t)c * 384 + 256 + q] = f2b(L * (1.0f - s) * INV_CQM);
  }
}

// per variable (both literals in one block): gathers + vgrad. sigm(vq) = exp2(-log2e*sp_neg).
// j-loop unrolled x4 -> 8 independent gathers in flight.
__global__ __launch_bounds__(256) void k_gatherv(const int* __restrict__ lptr, const int* __restrict__ lclause,
                                                 const bf16* __restrict__ cmA, const bf16* __restrict__ cd0,
                                                 const f16* __restrict__ spn, const float* __restrict__ dw,
                                                 const float* __restrict__ vdw, bf16* __restrict__ ugA) {
  int v = blockIdx.x;
  int half = threadIdx.x >> 7, q = threadIdx.x & 127;
  int l = v + half * NV;
  int j0 = lptr[l], j1 = lptr[l + 1];
  float sg = 0.0f, sv = 0.0f;
  for (int j = j0; j < j1; j += 4) {
#pragma unroll
    for (int k = 0; k < 4; ++k) {
      int jj = j + k;
      bool ok = jj < j1;
      int c = ok ? lclause[jj] : 0;
      float a = ok ? b2f(cmA[(size_t)c * 384 + 128 + q]) : 0.0f;
      float b = ok ? b2f(cd0[(size_t)c * 128 + q]) : 0.0f;
      sg += a;
      sv += b;
    }
  }
  __shared__ float sgl[2][128];
  sgl[half][q] = sg;
  ugA[(size_t)v * 512 + 256 + half * 128 + q] = f2b(sv * dw[l]);
  __syncthreads();
  if (half == 0) {
    float s = fexp2(-LOG2E * (float)spn[(size_t)v * 128 + q]);
    float g = ((1.0f - s) * sgl[1][q] - s * sgl[0][q]) * (INV_CQM * 0.25f) * vdw[v];
    ugA[(size_t)v * 512 + q] = f2b(g);
  }
}

template <typename T>
__global__ __launch_bounds__(256) void k_pn_stats(const T* __restrict__ X, int R, float* __restrict__ stats) {
  int q = threadIdx.x & 127;
  int rg = threadIdx.x >> 7;
  float cs = 0.0f, ss = 0.0f;
  for (int r = blockIdx.x * 2 + rg; r < R; r += gridDim.x * 2) {
    float x = cvt_ld(X[(size_t)r * 128 + q]);
    cs += x;
    ss += x * x;
  }
  __shared__ float scs[256], sss[256];
  scs[threadIdx.x] = cs;
  sss[threadIdx.x] = ss;
  __syncthreads();
  if (threadIdx.x < 128) atomicAdd(&stats[q], scs[q] + scs[128 + q]);
  for (int off = 128; off; off >>= 1) {
    if (threadIdx.x < off) sss[threadIdx.x] += sss[threadIdx.x + off];
    __syncthreads();
  }
  if (threadIdx.x == 0) atomicAdd(&stats[128], sss[0]);
}

__global__ __launch_bounds__(128) void k_pn_final(float* __restrict__ stats, float R) {
  __shared__ float s[128];
  int q = threadIdx.x;
  float m = stats[q] / R;
  s[q] = m * m;
  __syncthreads();
  for (int off = 64; off; off >>= 1) {
    if (q < off) s[q] += s[q + off];
    __syncthreads();
  }
  if (q == 0) {
    float var = (stats[128] - R * s[0]) / (R * 128.0f);
    stats[129] = rsqrtf(fmaxf(var, 0.0f) + 1e-6f) * 0.25f;
  }
  stats[q] = m;
}

__global__ __launch_bounds__(256) void k_pn_apply_c(const bf16* __restrict__ cd1, const float* __restrict__ stats,
                                                    bf16* __restrict__ cmA) {
  int i = blockIdx.x * 256 + threadIdx.x;
  int c = i >> 7, q = i & 127;
  float x = b2f(cd1[i]);
  float old = b2f(cmA[(size_t)c * 384 + q]);
  cmA[(size_t)c * 384 + q] = f2b((x - stats[q]) * stats[129] + 0.1f * old);
}

__global__ __launch_bounds__(256) void k_pn_apply_v(const float* __restrict__ uout, const float* __restrict__ stats,
                                                    float* __restrict__ variables, bf16* __restrict__ ugA) {
  int i = blockIdx.x * 256 + threadIdx.x;
  int v = i >> 7, q = i & 127;
  float nv = (uout[i] - stats[q]) * stats[129] + 0.1f * variables[i];
  variables[i] = nv;
  ugA[(size_t)v * 512 + 128 + q] = f2b(nv);
}

// ---------------- host ----------------

extern "C" void kernel_launch(void* const* d_in, const int* in_sizes, int n_in,
                              void* d_out, int out_size, void* d_ws, size_t ws_size,
                              hipStream_t stream) {
  const int* edge_lit = (const int*)d_in[0];
  const int* edge_clause = (const int*)d_in[1];
  const float* noise_v = (const float*)d_in[2];
  const float* noise_c = (const float*)d_in[3];
  const float* vq_w0 = (const float*)d_in[4];  const float* vq_b0 = (const float*)d_in[5];
  const float* vq_w1 = (const float*)d_in[6];  const float* vq_b1 = (const float*)d_in[7];
  const float* cq_w0 = (const float*)d_in[8];  const float* cq_b0 = (const float*)d_in[9];
  const float* cq_w1 = (const float*)d_in[10]; const float* cq_b1 = (const float*)d_in[11];
  const float* cm_w0 = (const float*)d_in[12]; const float* cm_b0 = (const float*)d_in[13];
  const float* cm_w1 = (const float*)d_in[14]; const float* cm_b1 = (const float*)d_in[15];
  const float* ug_w0 = (const float*)d_in[16]; const float* ug_b0 = (const float*)d_in[17];
  const float* ug_w1 = (const float*)d_in[18]; const float* ug_b1 = (const float*)d_in[19];
  const float* ug_w2 = (const float*)d_in[20]; const float* ug_b2 = (const float*)d_in[21];
  const float* co_w0 = (const float*)d_in[22]; const float* co_b0 = (const float*)d_in[23];
  const float* co_w1 = (const float*)d_in[24]; const float* co_b1 = (const float*)d_in[25];
  float* out = (float*)d_out;

  char* base = (char*)d_ws;
  size_t off = 0;
  auto A = [&](size_t n) -> char* {
    char* p = base + off;
    off = (off + n + 255) & ~(size_t)255;
    return p;
  };
  float* variables = (float*)A((size_t)NV * 128 * 4);
  bf16* cmA        = (bf16*)A((size_t)NC * 384 * 2);    // [clauses_h | loss4 | cg]
  bf16* ugA        = (bf16*)A((size_t)NV * 512 * 2);    // [vgrad | vars_h | vl_lo*dw | vl_hi*dw]
  char* R_cq       = A((size_t)NC * 128 * 2);           // cq | cd0
  char* R_h        = A((size_t)NC * 128 * 2);           // hv/hc | cd1 | uh1+uh2
  char* R_big      = A((size_t)2 * NV * 128 * 2 + (size_t)NV * 128 * 4);  // cmh | sp(2NV rows) -> uout
  bf16* wtb        = (bf16*)A(983424);
  int* cptr = (int*)A((size_t)(NC + 1) * 4);
  int* lptr = (int*)A((size_t)(2 * NV + 1) * 4);
  int* lcur = (int*)A((size_t)2 * NV * 4);
  int* lclause = (int*)A((size_t)NE * 4);
  float* dw  = (float*)A((size_t)2 * NV * 4);
  float* vdw = (float*)A((size_t)NV * 4);
  float* stats = (float*)A(2048);
  if (off > ws_size) {
    hipMemsetAsync(d_out, 0xFF, (size_t)out_size * 4, stream);
    return;
  }

  bf16* cq  = (bf16*)R_cq;
  bf16* cd0 = (bf16*)R_cq;
  bf16* hv  = (bf16*)R_h;
  bf16* hc  = (bf16*)R_h;
  bf16* cd1 = (bf16*)R_h;
  bf16* uh1 = (bf16*)R_h;
  bf16* uh2 = (bf16*)(R_h + (size_t)NV * 256 * 2);
  bf16* cmh = (bf16*)R_big;
  f16* spp  = (f16*)(R_big + 12582912);           // sp base (2NV rows); lives [vq1 .. k_gatherv]
  f16* spn  = spp + (size_t)NV * 128;
  float* uout = (float*)(R_big + 12582912);       // written after sp dead

  size_t wo = 0;
  auto WTa = [&](int n, int kp) { bf16* p = wtb + wo; wo += (size_t)n * kp; return p; };
  bf16* wt_vq0 = WTa(128, 192); bf16* wt_vq1 = WTa(128, 128);
  bf16* wt_cq0 = WTa(128, 192); bf16* wt_cq1 = WTa(128, 128);
  bf16* wt_cm0 = WTa(256, 384); bf16* wt_cm1 = WTa(256, 256);
  bf16* wt_ug0 = WTa(256, 512); bf16* wt_ug1 = WTa(256, 256);
  bf16* wt_ug2 = WTa(128, 256); bf16* wt_co0 = WTa(128, 128);

  hipMemsetAsync(lcur, 0, (size_t)2 * NV * 4, stream);
  k_cptr<<<(NC + 256) / 256, 256, 0, stream>>>(edge_clause, cptr);
  k_litcnt<<<NE / 256, 256, 0, stream>>>(edge_lit, lcur);
  k_scan<<<1, 1024, 0, stream>>>(lcur, lptr);
  k_fillsort<<<NE / 256, 256, 0, stream>>>(edge_lit, edge_clause, lcur, lclause);
  k_degree<<<(2 * NV + 255) / 256, 256, 0, stream>>>(lptr, dw, vdw);
  k_init_v<<<NV * 128 / 256, 256, 0, stream>>>(variables, ugA);
  k_init_c<<<NC * 128 / 256, 256, 0, stream>>>(cmA);
  k_wt<<<128 * 192 / 256, 256, 0, stream>>>(vq_w0, wt_vq0, 132, 128, 192);
  k_wt<<<128 * 128 / 256, 256, 0, stream>>>(vq_w1, wt_vq1, 128, 128, 128);
  k_wt<<<128 * 192 / 256, 256, 0, stream>>>(cq_w0, wt_cq0, 132, 128, 192);
  k_wt<<<128 * 128 / 256, 256, 0, stream>>>(cq_w1, wt_cq1, 128, 128, 128);
  k_wt<<<256 * 384 / 256, 256, 0, stream>>>(cm_w0, wt_cm0, 384, 256, 384);
  k_wt<<<256 * 256 / 256, 256, 0, stream>>>(cm_w1, wt_cm1, 256, 256, 256);
  k_wt<<<256 * 512 / 256, 256, 0, stream>>>(ug_w0, wt_ug0, 512, 256, 512);
  k_wt<<<256 * 256 / 256, 256, 0, stream>>>(ug_w1, wt_ug1, 256, 256, 256);
  k_wt<<<128 * 256 / 256, 256, 0, stream>>>(ug_w2, wt_ug2, 256, 128, 256);
  k_wt<<<128 * 128 / 256, 256, 0, stream>>>(co_w0, wt_co0, 128, 128, 128);

  for (int t = 0; t < 4; ++t) {
    const float* nvp = noise_v + (size_t)t * NV * 4;
    const float* ncp = noise_c + (size_t)t * NC * 4;
    // vq path: hv = relu([vars,nv]@W0+b0); softplus(+-(hv@W1+b1)) -> sp (f16)
    mgemm<192, true, true, 1><<<dim3(NV / 128, 1), 256, 0, stream>>>(ugA + 128, 512, nvp, wt_vq0, vq_b0, hv, nullptr, 128);
    mgemm<128, false, false, 3><<<dim3(NV / 128, 1), 256, 0, stream>>>(hv, 128, nullptr, wt_vq1, vq_b1, spp, spn, 128);
    // cq path
    mgemm<192, true, true, 1><<<dim3(NC / 128, 1), 256, 0, stream>>>(cmA, 384, ncp, wt_cq0, cq_b0, hc, nullptr, 128);
    mgemm<128, false, false, 1><<<dim3(NC / 128, 1), 256, 0, stream>>>(hc, 128, nullptr, wt_cq1, cq_b1, cq, nullptr, 128);
    k_loss<<<NC / 16, 256, 0, stream>>>(edge_lit, cptr, spp, cq, cmA);
    // clause_data = mlp2(cmA) — chunked
    for (int ch = 0; ch < NC / CMCHUNK; ++ch) {
      size_t ro = (size_t)ch * CMCHUNK;
      mgemm<384, false, true, 1><<<dim3(CMCHUNK / 128, 2), 256, 0, stream>>>(cmA + ro * 384, 384, nullptr, wt_cm0, cm_b0, cmh, nullptr, 256);
      mgemm<256, false, false, 2><<<dim3(CMCHUNK / 128, 2), 256, 0, stream>>>(cmh, 256, nullptr, wt_cm1, cm_b1, cd0 + ro * 128, cd1 + ro * 128, 128);
    }
    // merged gathers + vgrad (pair block per variable)
    k_gatherv<<<NV, 256, 0, stream>>>(lptr, lclause, cmA, cd0, spn, dw, vdw, ugA);
    // clauses = pair_norm(cd1)*0.25 + 0.1*clauses
    hipMemsetAsync(stats, 0, 132 * 4, stream);
    k_pn_stats<bf16><<<256, 256, 0, stream>>>(cd1, NC, stats);
    k_pn_final<<<1, 128, 0, stream>>>(stats, (float)NC);
    k_pn_apply_c<<<NC * 128 / 256, 256, 0, stream>>>(cd1, stats, cmA);
    // fused logits head: h = relu(clauses@co_w0+co_b0); logit = h.co_w1 + co_b1
    mgemm<128, false, false, 4><<<dim3(NC / 128, 1), 256, 0, stream>>>(cmA, 384, co_b1, wt_co0, co_b0, out, (void*)co_w1, t);
    // variables = pair_norm(mlp3(ugA))*0.25 + 0.1*variables
    mgemm<512, false, true, 1><<<dim3(NV / 128, 2), 256, 0, stream>>>(ugA, 512, nullptr, wt_ug0, ug_b0, uh1, nullptr, 256);
    mgemm<256, false, true, 1><<<dim3(NV / 128, 2), 256, 0, stream>>>(uh1, 256, nullptr, wt_ug1, ug_b1, uh2, nullptr, 256);
    mgemm<256, false, false, 0><<<dim3(NV / 128, 1), 256, 0, stream>>>(uh2, 256, nullptr, wt_ug2, ug_b2, uout, nullptr, 128);
    hipMemsetAsync(stats, 0, 132 * 4, stream);
    k_pn_stats<float><<<256, 256, 0, stream>>>(uout, NV, stats);
    k_pn_final<<<1, 128, 0, stream>>>(stats, (float)NV);
    k_pn_apply_v<<<NV * 128 / 256, 256, 0, stream>>>(uout, stats, variables, ugA);
  }
}

// Round 7
// 1903.006 us; speedup vs baseline: 3.3401x; 1.0194x over previous
//
#include <hip/hip_runtime.h>
#include <math.h>

#define NV 24576
#define NC 98304
#define NE 294912
#define CMCHUNK 24576  // 4 chunks over NC

typedef unsigned short bf16;
typedef _Float16 f16;
using bf8 = __attribute__((ext_vector_type(8))) short;
using f4  = __attribute__((ext_vector_type(4))) float;

static constexpr float INV_CQM = 1.0f / 12582912.0f;  // 1/(NC*128)
static constexpr float LOG2E = 1.44269504f;
static constexpr float LN2 = 0.69314718f;

__device__ __forceinline__ float b2f(bf16 h) { return __uint_as_float(((unsigned)h) << 16); }
__device__ __forceinline__ bf16 f2b(float f) {
  unsigned u = __float_as_uint(f);
  u += 0x7fff + ((u >> 16) & 1);  // RNE
  return (bf16)(u >> 16);
}
__device__ __forceinline__ float fexp2(float x) { float r; asm("v_exp_f32 %0, %1" : "=v"(r) : "v"(x)); return r; }
__device__ __forceinline__ float flog2(float x) { float r; asm("v_log_f32 %0, %1" : "=v"(r) : "v"(x)); return r; }
__device__ __forceinline__ float frcpf(float x) { float r; asm("v_rcp_f32 %0, %1" : "=v"(r) : "v"(x)); return r; }
__device__ __forceinline__ float fsigm(float x) { return frcpf(1.0f + fexp2(-x * LOG2E)); }
__device__ __forceinline__ float fsoftplus(float x) {
  return fmaxf(x, 0.0f) + LN2 * flog2(1.0f + fexp2(-fabsf(x) * LOG2E));
}
__device__ __forceinline__ float cvt_ld(float x) { return x; }
__device__ __forceinline__ float cvt_ld(bf16 x) { return b2f(x); }

__device__ __forceinline__ void gload16(const void* g, void* l) {
  __builtin_amdgcn_global_load_lds((const __attribute__((address_space(1))) unsigned int*)g,
                                   (__attribute__((address_space(3))) unsigned int*)l, 16, 0, 0);
}

// ---------------- precompute kernels ----------------

__global__ __launch_bounds__(256) void k_cptr(const int* __restrict__ ec, int* __restrict__ ptr) {
  int c = blockIdx.x * 256 + threadIdx.x;
  if (c > NC) return;
  int lo = 0, hi = NE;
  while (lo < hi) { int mid = (lo + hi) >> 1; if (ec[mid] < c) lo = mid + 1; else hi = mid; }
  ptr[c] = lo;
}

__global__ __launch_bounds__(256) void k_litcnt(const int* __restrict__ el, int* __restrict__ cnt) {
  int e = blockIdx.x * 256 + threadIdx.x;
  atomicAdd(&cnt[el[e]], 1);
}

__global__ __launch_bounds__(1024) void k_scan(int* __restrict__ cnt, int* __restrict__ ptr) {
  __shared__ int wsum[16];
  __shared__ int carry_s;
  int tid = threadIdx.x, lane = tid & 63, w = tid >> 6;
  if (tid == 0) carry_s = 0;
  __syncthreads();
  for (int base = 0; base < 2 * NV; base += 1024) {
    int x = cnt[base + tid];
    int v = x;
#pragma unroll
    for (int off = 1; off < 64; off <<= 1) {
      int y = __shfl_up(v, off, 64);
      if (lane >= off) v += y;
    }
    if (lane == 63) wsum[w] = v;
    __syncthreads();
    int carry = carry_s;
    int wpre = 0;
    for (int i = 0; i < w; ++i) wpre += wsum[i];
    int excl = carry + wpre + (v - x);
    ptr[base + tid] = excl;
    cnt[base + tid] = excl;
    __syncthreads();
    if (tid == 1023) carry_s = carry + wpre + v;
  }
  __syncthreads();
  if (tid == 0) ptr[2 * NV] = carry_s;
}

__global__ __launch_bounds__(256) void k_fillsort(const int* __restrict__ el, const int* __restrict__ ec,
                                                  int* __restrict__ cur, int* __restrict__ lclause) {
  int e = blockIdx.x * 256 + threadIdx.x;
  int pos = atomicAdd(&cur[el[e]], 1);
  lclause[pos] = ec[e];
}

__global__ __launch_bounds__(256) void k_degree(const int* __restrict__ lptr, float* __restrict__ dw,
                                                float* __restrict__ vdw) {
  int l = blockIdx.x * 256 + threadIdx.x;
  if (l < 2 * NV) dw[l] = rsqrtf(fmaxf((float)(lptr[l + 1] - lptr[l]), 1.0f));
  if (l < NV) {
    int d = (lptr[l + 1] - lptr[l]) + (lptr[l + NV + 1] - lptr[l + NV]);
    vdw[l] = 4.0f * rsqrtf(fmaxf((float)d, 1.0f));
  }
}

__global__ __launch_bounds__(256) void k_init_v(float* __restrict__ variables, bf16* __restrict__ ugA) {
  int i = blockIdx.x * 256 + threadIdx.x;
  variables[i] = 1.0f;
  ugA[(size_t)(i >> 7) * 512 + 128 + (i & 127)] = 0x3F80;
}
__global__ __launch_bounds__(256) void k_init_c(bf16* __restrict__ cmA) {
  int i = blockIdx.x * 256 + threadIdx.x;
  cmA[(size_t)(i >> 7) * 256 + (i & 127)] = 0x3F80;
}

__global__ __launch_bounds__(256) void k_wt(const float* __restrict__ w, bf16* __restrict__ wt,
                                            int K, int N, int Kpad) {
  int idx = blockIdx.x * 256 + threadIdx.x;
  int n = idx / Kpad, k = idx % Kpad;
  if (n >= N) return;
  wt[idx] = (k < K) ? f2b(w[(size_t)k * N + n]) : (bf16)0;
}

// ---------------- MFMA GEMM body: 128x128 tile, 4 waves, BK=64, 2-phase dbuf ----------------
// AL: AL_STD (all K-tiles from A0), AL_NOISE (tiles 0,1 from A0; tile 2 = noise f32 cols 0-3 pad 0),
//     AL_CM (tiles 0,1: A0 cols k0; tiles 2,3: A1 cols k0-128; tiles 4,5: A0 cols k0-128; lda=256).
// OUT: 0=f32, 1=bf16 (ldOut), 2=dual bf16 (o0 ld 256, o1 ld 128, split col 128),
//      3=softplus pair f16 (o0/o1 ld 128), 4=fused logits head (o0=out, o1=w1, noise[0]=b1, ldOut=t).

struct GP {
  const bf16* A0; const bf16* A1; int lda;
  const float* noise; const bf16* WT; const float* Bv;
  void* o0; void* o1; int ldOut;
};

enum { AL_STD = 0, AL_NOISE = 1, AL_CM = 2 };

template <int KDIM, int AL, bool RELU, int OUT>
__device__ __forceinline__ void gemm_body(const GP g, int bx, char* smem) {
  constexpr int NT = KDIM / 64;
  const int tid = threadIdx.x;
  const int m0 = bx * 128;
  const int n0 = blockIdx.y * 128;
  const int lane = tid & 63;
  const int w = tid >> 6;
  const int wr = w >> 1, wc = w & 1;
  const int rl = (tid >> 3) & 7;
  const int cc = tid & 7;
  const int swzoff = (cc * 16) ^ (rl << 4);

  auto stage = [&](int t, int buf) {
    char* As = smem + buf * 32768;
    char* Bs = As + 16384;
    const int k0 = t * 64;
    if (AL == AL_NOISE && t == 2) {  // noise columns: reg-stage A, gload B
      const int srow = tid >> 3, schunk = tid & 7;
#pragma unroll
      for (int it = 0; it < 4; ++it) {
        int row = srow + it * 32;
        alignas(16) bf16 tmp[8];
#pragma unroll
        for (int e = 0; e < 8; ++e) {
          int kk = schunk * 8 + e;
          tmp[e] = (kk < 4) ? f2b(g.noise[(size_t)(m0 + row) * 4 + kk]) : (bf16)0;
        }
        *reinterpret_cast<uint4*>(&As[row * 128 + ((schunk * 16) ^ ((row & 7) << 4))]) =
            *reinterpret_cast<uint4*>(tmp);
        int row0 = it * 32 + w * 8;
        gload16((const char*)(g.WT + (size_t)(n0 + row0 + rl) * KDIM + k0) + swzoff, Bs + row0 * 128);
      }
    } else {
      const bf16* Ap = g.A0;
      int co_ = k0;
      if (AL == AL_CM) {
        if (t >= 2 && t < 4) Ap = g.A1;
        if (t >= 2) co_ = k0 - 128;
      }
#pragma unroll
      for (int it = 0; it < 4; ++it) {
        int row0 = it * 32 + w * 8;
        int row = row0 + rl;
        gload16((const char*)(Ap + (size_t)(m0 + row) * g.lda + co_) + swzoff, As + row0 * 128);
        gload16((const char*)(g.WT + (size_t)(n0 + row) * KDIM + k0) + swzoff, Bs + row0 * 128);
      }
    }
  };

  f4 acc[4][4] = {};
  stage(0, 0);
#pragma unroll
  for (int t = 0; t < NT; ++t) {
    const int buf = t & 1;
    __builtin_amdgcn_sched_barrier(0);
    if (t + 1 < NT) {
      stage(t + 1, buf ^ 1);
      if (AL == AL_NOISE && t + 1 == 2) {
        asm volatile("s_waitcnt vmcnt(4) lgkmcnt(0)" ::: "memory");
      } else {
        asm volatile("s_waitcnt vmcnt(8) lgkmcnt(0)" ::: "memory");
      }
    } else {
      asm volatile("s_waitcnt vmcnt(0) lgkmcnt(0)" ::: "memory");
    }
    __builtin_amdgcn_s_barrier();
    __builtin_amdgcn_sched_barrier(0);
    const char* As = smem + buf * 32768;
    const char* Bs = As + 16384;
#pragma unroll
    for (int kk = 0; kk < 2; ++kk) {
      bf8 a[4], b[4];
#pragma unroll
      for (int i = 0; i < 4; ++i) {
        int r = wr * 64 + i * 16 + (lane & 15);
        int cby = (kk * 64 + ((lane >> 4) * 16)) ^ ((r & 7) << 4);
        a[i] = *reinterpret_cast<const bf8*>(&As[r * 128 + cby]);
        int c = wc * 64 + i * 16 + (lane & 15);
        int cby2 = (kk * 64 + ((lane >> 4) * 16)) ^ ((c & 7) << 4);
        b[i] = *reinterpret_cast<const bf8*>(&Bs[c * 128 + cby2]);
      }
#pragma unroll
      for (int i = 0; i < 4; ++i)
#pragma unroll
        for (int j = 0; j < 4; ++j)
          acc[i][j] = __builtin_amdgcn_mfma_f32_16x16x32_bf16(a[i], b[j], acc[i][j], 0, 0, 0);
    }
    __builtin_amdgcn_sched_barrier(0);
    __builtin_amdgcn_s_barrier();
  }
  const int colloc = wc * 64 + (lane & 15);
  const int rowbase = m0 + wr * 64 + ((lane >> 4) << 2);

  if constexpr (OUT == 4) {
    const float* w1 = (const float*)g.o1;
    float* outp = (float*)g.o0;
    const int t = g.ldOut;
    float part[4][4];
#pragma unroll
    for (int i = 0; i < 4; ++i)
#pragma unroll
      for (int p = 0; p < 4; ++p) part[i][p] = 0.0f;
#pragma unroll
    for (int j = 0; j < 4; ++j) {
      int c = colloc + j * 16;
      float bias = g.Bv[c];
      float w1c = w1[c];
#pragma unroll
      for (int i = 0; i < 4; ++i)
#pragma unroll
        for (int p = 0; p < 4; ++p)
          part[i][p] += fmaxf(acc[i][j][p] + bias, 0.0f) * w1c;
    }
#pragma unroll
    for (int m = 1; m < 16; m <<= 1)
#pragma unroll
      for (int i = 0; i < 4; ++i)
#pragma unroll
        for (int p = 0; p < 4; ++p)
          part[i][p] += __shfl_xor(part[i][p], m, 64);
    float* red = (float*)smem;
    if ((lane & 15) == 0) {
#pragma unroll
      for (int i = 0; i < 4; ++i)
#pragma unroll
        for (int p = 0; p < 4; ++p)
          red[wc * 128 + wr * 64 + i * 16 + ((lane >> 4) << 2) + p] = part[i][p];
    }
    __syncthreads();
    if (tid < 128) {
      float lg = red[tid] + red[128 + tid] + g.noise[0];
      int row = m0 + tid;
      outp[(size_t)t * NC + row] = fsigm(lg);
      outp[(size_t)4 * NC + (size_t)t * NC + row] = fsoftplus(lg);
    }
    return;
  }

#pragma unroll
  for (int j = 0; j < 4; ++j) {
    int c = n0 + colloc + j * 16;
    float bias = g.Bv[c];
#pragma unroll
    for (int i = 0; i < 4; ++i) {
      int rb = rowbase + i * 16;
#pragma unroll
      for (int p = 0; p < 4; ++p) {
        float v = acc[i][j][p] + bias;
        if (RELU) v = fmaxf(v, 0.0f);
        int r = rb + p;
        if constexpr (OUT == 0) {
          ((float*)g.o0)[(size_t)r * g.ldOut + c] = v;
        } else if constexpr (OUT == 1) {
          ((bf16*)g.o0)[(size_t)r * g.ldOut + c] = f2b(v);
        } else if constexpr (OUT == 2) {
          if (c < 128) ((bf16*)g.o0)[(size_t)r * 256 + c] = f2b(v);
          else ((bf16*)g.o1)[(size_t)r * 128 + (c - 128)] = f2b(v);
        } else {  // OUT==3
          float tq = LN2 * flog2(1.0f + fexp2(-fabsf(v) * LOG2E));
          ((f16*)g.o0)[(size_t)r * 128 + c] = (f16)(fmaxf(v, 0.0f) + tq);
          ((f16*)g.o1)[(size_t)r * 128 + c] = (f16)(fmaxf(-v, 0.0f) + tq);
        }
      }
    }
  }
}

template <int KDIM, int AL, bool RELU, int OUT>
__global__ __launch_bounds__(256) void mgemm_s(GP g) {
  __shared__ __align__(16) char smem[65536];
  gemm_body<KDIM, AL, RELU, OUT>(g, blockIdx.x, smem);
}

template <int KDIM, int AL, bool RELU, int OUTA, int OUTB>
__global__ __launch_bounds__(256) void mgemm_d(GP ga, GP gb, int nA) {
  __shared__ __align__(16) char smem[65536];
  if ((int)blockIdx.x < nA) gemm_body<KDIM, AL, RELU, OUTA>(ga, blockIdx.x, smem);
  else gemm_body<KDIM, AL, RELU, OUTB>(gb, blockIdx.x - nA, smem);
}

// ---------------- graph / elementwise kernels ----------------

// per clause: csum over precomputed softplus; reads cq from gbuf[c][128+q];
// writes loss4 -> gbuf[c][q], cg -> cmA[c][128+q].
__global__ __launch_bounds__(256) void k_loss(const int* __restrict__ edge_lit, const int* __restrict__ cptr,
                                              const f16* __restrict__ sp, bf16* __restrict__ gbuf,
                                              bf16* __restrict__ cmA) {
  const int g = threadIdx.x >> 7;
  const int q = threadIdx.x & 127;
  const int c0 = blockIdx.x * 16 + g * 8;
#pragma unroll
  for (int ci = 0; ci < 8; ++ci) {
    int c = c0 + ci;
    int e0 = cptr[c], e1 = cptr[c + 1];
    float csum = 0.0f;
    for (int e = e0; e < e1; e += 4) {
#pragma unroll
      for (int k = 0; k < 4; ++k) {
        int ee = e + k;
        bool ok = ee < e1;
        int lit = ok ? edge_lit[ee] : 0;
        float v = ok ? (float)sp[(size_t)lit * 128 + q] : 0.0f;
        csum += v;
      }
    }
    float s = fsigm(b2f(gbuf[(size_t)c * 256 + 128 + q]));
    float L = fexp2(-csum * LOG2E) * s;
    gbuf[(size_t)c * 256 + q] = f2b(4.0f * L);
    cmA[(size_t)c * 256 + 128 + q] = f2b(L * (1.0f - s) * INV_CQM);
  }
}

// per variable: gathers from interleaved gbuf rows (512B contiguous per clause) + vgrad.
__global__ __launch_bounds__(256) void k_gatherv(const int* __restrict__ lptr, const int* __restrict__ lclause,
                                                 const bf16* __restrict__ gbuf, const f16* __restrict__ spn,
                                                 const float* __restrict__ dw, const float* __restrict__ vdw,
                                                 bf16* __restrict__ ugA) {
  int v = blockIdx.x;
  int half = threadIdx.x >> 7, q = threadIdx.x & 127;
  int l = v + half * NV;
  int j0 = lptr[l], j1 = lptr[l + 1];
  float sg = 0.0f, sv = 0.0f;
  for (int j = j0; j < j1; j += 4) {
#pragma unroll
    for (int k = 0; k < 4; ++k) {
      int jj = j + k;
      bool ok = jj < j1;
      int c = ok ? lclause[jj] : 0;
      float a = ok ? b2f(gbuf[(size_t)c * 256 + q]) : 0.0f;
      float b = ok ? b2f(gbuf[(size_t)c * 256 + 128 + q]) : 0.0f;
      sg += a;
      sv += b;
    }
  }
  __shared__ float sgl[2][128];
  sgl[half][q] = sg;
  ugA[(size_t)v * 512 + 256 + half * 128 + q] = f2b(sv * dw[l]);
  __syncthreads();
  if (half == 0) {
    float s = fexp2(-LOG2E * (float)spn[(size_t)v * 128 + q]);
    float g = ((1.0f - s) * sgl[1][q] - s * sgl[0][q]) * (INV_CQM * 0.25f) * vdw[v];
    ugA[(size_t)v * 512 + q] = f2b(g);
  }
}

template <typename T>
__global__ __launch_bounds__(256) void k_pn_stats(const T* __restrict__ X, int R, float* __restrict__ stats) {
  int q = threadIdx.x & 127;
  int rg = threadIdx.x >> 7;
  float cs = 0.0f, ss = 0.0f;
  for (int r = blockIdx.x * 2 + rg; r < R; r += gridDim.x * 2) {
    float x = cvt_ld(X[(size_t)r * 128 + q]);
    cs += x;
    ss += x * x;
  }
  __shared__ float scs[256], sss[256];
  scs[threadIdx.x] = cs;
  sss[threadIdx.x] = ss;
  __syncthreads();
  if (threadIdx.x < 128) atomicAdd(&stats[q], scs[q] + scs[128 + q]);
  for (int off = 128; off; off >>= 1) {
    if (threadIdx.x < off) sss[threadIdx.x] += sss[threadIdx.x + off];
    __syncthreads();
  }
  if (threadIdx.x == 0) atomicAdd(&stats[128], sss[0]);
}

__global__ __launch_bounds__(128) void k_pn_final(float* __restrict__ stats, float R) {
  __shared__ float s[128];
  int q = threadIdx.x;
  float m = stats[q] / R;
  s[q] = m * m;
  __syncthreads();
  for (int off = 64; off; off >>= 1) {
    if (q < off) s[q] += s[q + off];
    __syncthreads();
  }
  if (q == 0) {
    float var = (stats[128] - R * s[0]) / (R * 128.0f);
    stats[129] = rsqrtf(fmaxf(var, 0.0f) + 1e-6f) * 0.25f;
  }
  stats[q] = m;
}

__global__ __launch_bounds__(256) void k_pn_apply_c(const bf16* __restrict__ cd1, const float* __restrict__ stats,
                                                    bf16* __restrict__ cmA) {
  int i = blockIdx.x * 256 + threadIdx.x;
  int c = i >> 7, q = i & 127;
  float x = b2f(cd1[i]);
  float old = b2f(cmA[(size_t)c * 256 + q]);
  cmA[(size_t)c * 256 + q] = f2b((x - stats[q]) * stats[129] + 0.1f * old);
}

__global__ __launch_bounds__(256) void k_pn_apply_v(const float* __restrict__ uout, const float* __restrict__ stats,
                                                    float* __restrict__ variables, bf16* __restrict__ ugA) {
  int i = blockIdx.x * 256 + threadIdx.x;
  int v = i >> 7, q = i & 127;
  float nv = (uout[i] - stats[q]) * stats[129] + 0.1f * variables[i];
  variables[i] = nv;
  ugA[(size_t)v * 512 + 128 + q] = f2b(nv);
}

// ---------------- host ----------------

extern "C" void kernel_launch(void* const* d_in, const int* in_sizes, int n_in,
                              void* d_out, int out_size, void* d_ws, size_t ws_size,
                              hipStream_t stream) {
  const int* edge_lit = (const int*)d_in[0];
  const int* edge_clause = (const int*)d_in[1];
  const float* noise_v = (const float*)d_in[2];
  const float* noise_c = (const float*)d_in[3];
  const float* vq_w0 = (const float*)d_in[4];  const float* vq_b0 = (const float*)d_in[5];
  const float* vq_w1 = (const float*)d_in[6];  const float* vq_b1 = (const float*)d_in[7];
  const float* cq_w0 = (const float*)d_in[8];  const float* cq_b0 = (const float*)d_in[9];
  const float* cq_w1 = (const float*)d_in[10]; const float* cq_b1 = (const float*)d_in[11];
  const float* cm_w0 = (const float*)d_in[12]; const float* cm_b0 = (const float*)d_in[13];
  const float* cm_w1 = (const float*)d_in[14]; const float* cm_b1 = (const float*)d_in[15];
  const float* ug_w0 = (const float*)d_in[16]; const float* ug_b0 = (const float*)d_in[17];
  const float* ug_w1 = (const float*)d_in[18]; const float* ug_b1 = (const float*)d_in[19];
  const float* ug_w2 = (const float*)d_in[20]; const float* ug_b2 = (const float*)d_in[21];
  const float* co_w0 = (const float*)d_in[22]; const float* co_b0 = (const float*)d_in[23];
  const float* co_w1 = (const float*)d_in[24]; const float* co_b1 = (const float*)d_in[25];
  float* out = (float*)d_out;

  char* base = (char*)d_ws;
  size_t off = 0;
  auto A = [&](size_t n) -> char* {
    char* p = base + off;
    off = (off + n + 255) & ~(size_t)255;
    return p;
  };
  float* variables = (float*)A((size_t)NV * 128 * 4);
  bf16* cmA        = (bf16*)A((size_t)NC * 256 * 2);    // [clauses_h | cg]
  bf16* gbuf       = (bf16*)A((size_t)NC * 256 * 2);    // [loss4 | cq->cd0] interleaved gather buffer
  bf16* ugA        = (bf16*)A((size_t)NV * 512 * 2);    // [vgrad | vars_h | vl_lo*dw | vl_hi*dw]
  char* R_h        = A((size_t)NC * 128 * 2);           // hc | cd1 | uh1+uh2
  char* R_big      = A((size_t)2 * NV * 128 * 2 + (size_t)NV * 128 * 4);  // hv/cmh | sp -> uout
  bf16* wtb        = (bf16*)A(983424);
  int* cptr = (int*)A((size_t)(NC + 1) * 4);
  int* lptr = (int*)A((size_t)(2 * NV + 1) * 4);
  int* lcur = (int*)A((size_t)2 * NV * 4);
  int* lclause = (int*)A((size_t)NE * 4);
  float* dw  = (float*)A((size_t)2 * NV * 4);
  float* vdw = (float*)A((size_t)NV * 4);
  float* stats = (float*)A(2048);
  if (off > ws_size) {
    hipMemsetAsync(d_out, 0xFF, (size_t)out_size * 4, stream);
    return;
  }

  bf16* hc  = (bf16*)R_h;                          // NC x 128
  bf16* cd1 = (bf16*)R_h;
  bf16* uh1 = (bf16*)R_h;
  bf16* uh2 = (bf16*)(R_h + (size_t)NV * 256 * 2);
  bf16* hv  = (bf16*)R_big;                        // NV x 128 (dead before cmh use)
  bf16* cmh = (bf16*)R_big;                        // CMCHUNK x 256
  f16* spp  = (f16*)(R_big + 12582912);            // 2NV x 128 f16; lives [vq1 .. k_gatherv]
  f16* spn  = spp + (size_t)NV * 128;
  float* uout = (float*)(R_big + 12582912);        // after sp dead

  size_t wo = 0;
  auto WTa = [&](int n, int kp) { bf16* p = wtb + wo; wo += (size_t)n * kp; return p; };
  bf16* wt_vq0 = WTa(128, 192); bf16* wt_vq1 = WTa(128, 128);
  bf16* wt_cq0 = WTa(128, 192); bf16* wt_cq1 = WTa(128, 128);
  bf16* wt_cm0 = WTa(256, 384); bf16* wt_cm1 = WTa(256, 256);
  bf16* wt_ug0 = WTa(256, 512); bf16* wt_ug1 = WTa(256, 256);
  bf16* wt_ug2 = WTa(128, 256); bf16* wt_co0 = WTa(128, 128);

  hipMemsetAsync(lcur, 0, (size_t)2 * NV * 4, stream);
  k_cptr<<<(NC + 256) / 256, 256, 0, stream>>>(edge_clause, cptr);
  k_litcnt<<<NE / 256, 256, 0, stream>>>(edge_lit, lcur);
  k_scan<<<1, 1024, 0, stream>>>(lcur, lptr);
  k_fillsort<<<NE / 256, 256, 0, stream>>>(edge_lit, edge_clause, lcur, lclause);
  k_degree<<<(2 * NV + 255) / 256, 256, 0, stream>>>(lptr, dw, vdw);
  k_init_v<<<NV * 128 / 256, 256, 0, stream>>>(variables, ugA);
  k_init_c<<<NC * 128 / 256, 256, 0, stream>>>(cmA);
  k_wt<<<128 * 192 / 256, 256, 0, stream>>>(vq_w0, wt_vq0, 132, 128, 192);
  k_wt<<<128 * 128 / 256, 256, 0, stream>>>(vq_w1, wt_vq1, 128, 128, 128);
  k_wt<<<128 * 192 / 256, 256, 0, stream>>>(cq_w0, wt_cq0, 132, 128, 192);
  k_wt<<<128 * 128 / 256, 256, 0, stream>>>(cq_w1, wt_cq1, 128, 128, 128);
  k_wt<<<256 * 384 / 256, 256, 0, stream>>>(cm_w0, wt_cm0, 384, 256, 384);
  k_wt<<<256 * 256 / 256, 256, 0, stream>>>(cm_w1, wt_cm1, 256, 256, 256);
  k_wt<<<256 * 512 / 256, 256, 0, stream>>>(ug_w0, wt_ug0, 512, 256, 512);
  k_wt<<<256 * 256 / 256, 256, 0, stream>>>(ug_w1, wt_ug1, 256, 256, 256);
  k_wt<<<128 * 256 / 256, 256, 0, stream>>>(ug_w2, wt_ug2, 256, 128, 256);
  k_wt<<<128 * 128 / 256, 256, 0, stream>>>(co_w0, wt_co0, 128, 128, 128);

  for (int t = 0; t < 4; ++t) {
    const float* nvp = noise_v + (size_t)t * NV * 4;
    const float* ncp = noise_c + (size_t)t * NC * 4;
    // merged layer-0: vq0 (192 blocks) + cq0 (768 blocks)
    {
      GP pa{ugA + 128, nullptr, 512, nvp, wt_vq0, vq_b0, hv, nullptr, 128};
      GP pb{cmA, nullptr, 256, ncp, wt_cq0, cq_b0, hc, nullptr, 128};
      mgemm_d<192, AL_NOISE, true, 1, 1><<<dim3(960, 1), 256, 0, stream>>>(pa, pb, 192);
    }
    // merged layer-1: vq1 -> softplus pair f16 (OUT=3) + cq1 -> gbuf cq slot (OUT=1, ld 256)
    {
      GP pa{hv, nullptr, 128, nullptr, wt_vq1, vq_b1, spp, spn, 128};
      GP pb{hc, nullptr, 128, nullptr, wt_cq1, cq_b1, gbuf + 128, nullptr, 256};
      mgemm_d<128, AL_STD, false, 3, 1><<<dim3(960, 1), 256, 0, stream>>>(pa, pb, 192);
    }
    k_loss<<<NC / 16, 256, 0, stream>>>(edge_lit, cptr, spp, gbuf, cmA);
    // clause_data MLP — chunked; A tiles: [clauses(cmA) | loss4(gbuf) | cg(cmA+128)]
    for (int ch = 0; ch < NC / CMCHUNK; ++ch) {
      size_t ro = (size_t)ch * CMCHUNK;
      GP p0{cmA + ro * 256, gbuf + ro * 256, 256, nullptr, wt_cm0, cm_b0, cmh, nullptr, 256};
      mgemm_s<384, AL_CM, true, 1><<<dim3(CMCHUNK / 128, 2), 256, 0, stream>>>(p0);
      GP p1{cmh, nullptr, 256, nullptr, wt_cm1, cm_b1, gbuf + ro * 256 + 128, cd1 + ro * 128, 0};
      mgemm_s<256, AL_STD, false, 2><<<dim3(CMCHUNK / 128, 2), 256, 0, stream>>>(p1);
    }
    // merged gathers + vgrad from interleaved gbuf
    k_gatherv<<<NV, 256, 0, stream>>>(lptr, lclause, gbuf, spn, dw, vdw, ugA);
    // clauses = pair_norm(cd1)*0.25 + 0.1*clauses
    hipMemsetAsync(stats, 0, 132 * 4, stream);
    k_pn_stats<bf16><<<256, 256, 0, stream>>>(cd1, NC, stats);
    k_pn_final<<<1, 128, 0, stream>>>(stats, (float)NC);
    k_pn_apply_c<<<NC * 128 / 256, 256, 0, stream>>>(cd1, stats, cmA);
    // fused logits head
    {
      GP p{cmA, nullptr, 256, co_b1, wt_co0, co_b0, out, (void*)co_w1, t};
      mgemm_s<128, AL_STD, false, 4><<<dim3(NC / 128, 1), 256, 0, stream>>>(p);
    }
    // variables = pair_norm(mlp3(ugA))*0.25 + 0.1*variables
    {
      GP p{ugA, nullptr, 512, nullptr, wt_ug0, ug_b0, uh1, nullptr, 256};
      mgemm_s<512, AL_STD, true, 1><<<dim3(NV / 128, 2), 256, 0, stream>>>(p);
    }
    {
      GP p{uh1, nullptr, 256, nullptr, wt_ug1, ug_b1, uh2, nullptr, 256};
      mgemm_s<256, AL_STD, true, 1><<<dim3(NV / 128, 2), 256, 0, stream>>>(p);
    }
    {
      GP p{uh2, nullptr, 256, nullptr, wt_ug2, ug_b2, uout, nullptr, 128};
      mgemm_s<256, AL_STD, false, 0><<<dim3(NV / 128, 1), 256, 0, stream>>>(p);
    }
    hipMemsetAsync(stats, 0, 132 * 4, stream);
    k_pn_stats<float><<<256, 256, 0, stream>>>(uout, NV, stats);
    k_pn_final<<<1, 128, 0, stream>>>(stats, (float)NV);
    k_pn_apply_v<<<NV * 128 / 256, 256, 0, stream>>>(uout, stats, variables, ugA);
  }
}

// Round 8
// 1688.992 us; speedup vs baseline: 3.7633x; 1.1267x over previous
//
#include <hip/hip_runtime.h>
#include <math.h>

#define NV 24576
#define NC 98304
#define NE 294912
#define CMCHUNK 49152  // 2 chunks over NC

typedef unsigned short bf16;
typedef _Float16 f16;
using bf8 = __attribute__((ext_vector_type(8))) short;
using f4  = __attribute__((ext_vector_type(4))) float;

static constexpr float INV_CQM = 1.0f / 12582912.0f;  // 1/(NC*128)
static constexpr float LOG2E = 1.44269504f;
static constexpr float LN2 = 0.69314718f;

__device__ __forceinline__ float b2f(bf16 h) { return __uint_as_float(((unsigned)h) << 16); }
__device__ __forceinline__ bf16 f2b(float f) {
  unsigned u = __float_as_uint(f);
  u += 0x7fff + ((u >> 16) & 1);  // RNE
  return (bf16)(u >> 16);
}
__device__ __forceinline__ float fexp2(float x) { float r; asm("v_exp_f32 %0, %1" : "=v"(r) : "v"(x)); return r; }
__device__ __forceinline__ float flog2(float x) { float r; asm("v_log_f32 %0, %1" : "=v"(r) : "v"(x)); return r; }
__device__ __forceinline__ float frcpf(float x) { float r; asm("v_rcp_f32 %0, %1" : "=v"(r) : "v"(x)); return r; }
__device__ __forceinline__ float fsigm(float x) { return frcpf(1.0f + fexp2(-x * LOG2E)); }
__device__ __forceinline__ float fsoftplus(float x) {
  return fmaxf(x, 0.0f) + LN2 * flog2(1.0f + fexp2(-fabsf(x) * LOG2E));
}

__device__ __forceinline__ void gload16(const void* g, void* l) {
  __builtin_amdgcn_global_load_lds((const __attribute__((address_space(1))) unsigned int*)g,
                                   (__attribute__((address_space(3))) unsigned int*)l, 16, 0, 0);
}

// ---------------- precompute kernels ----------------

__global__ __launch_bounds__(256) void k_cptr(const int* __restrict__ ec, int* __restrict__ ptr) {
  int c = blockIdx.x * 256 + threadIdx.x;
  if (c > NC) return;
  int lo = 0, hi = NE;
  while (lo < hi) { int mid = (lo + hi) >> 1; if (ec[mid] < c) lo = mid + 1; else hi = mid; }
  ptr[c] = lo;
}

__global__ __launch_bounds__(256) void k_litcnt(const int* __restrict__ el, int* __restrict__ cnt) {
  int e = blockIdx.x * 256 + threadIdx.x;
  atomicAdd(&cnt[el[e]], 1);
}

__global__ __launch_bounds__(1024) void k_scan(int* __restrict__ cnt, int* __restrict__ ptr) {
  __shared__ int wsum[16];
  __shared__ int carry_s;
  int tid = threadIdx.x, lane = tid & 63, w = tid >> 6;
  if (tid == 0) carry_s = 0;
  __syncthreads();
  for (int base = 0; base < 2 * NV; base += 1024) {
    int x = cnt[base + tid];
    int v = x;
#pragma unroll
    for (int off = 1; off < 64; off <<= 1) {
      int y = __shfl_up(v, off, 64);
      if (lane >= off) v += y;
    }
    if (lane == 63) wsum[w] = v;
    __syncthreads();
    int carry = carry_s;
    int wpre = 0;
    for (int i = 0; i < w; ++i) wpre += wsum[i];
    int excl = carry + wpre + (v - x);
    ptr[base + tid] = excl;
    cnt[base + tid] = excl;
    __syncthreads();
    if (tid == 1023) carry_s = carry + wpre + v;
  }
  __syncthreads();
  if (tid == 0) ptr[2 * NV] = carry_s;
}

__global__ __launch_bounds__(256) void k_fillsort(const int* __restrict__ el, const int* __restrict__ ec,
                                                  int* __restrict__ cur, int* __restrict__ lclause) {
  int e = blockIdx.x * 256 + threadIdx.x;
  int pos = atomicAdd(&cur[el[e]], 1);
  lclause[pos] = ec[e];
}

__global__ __launch_bounds__(256) void k_degree(const int* __restrict__ lptr, float* __restrict__ dw,
                                                float* __restrict__ vdw) {
  int l = blockIdx.x * 256 + threadIdx.x;
  if (l < 2 * NV) dw[l] = rsqrtf(fmaxf((float)(lptr[l + 1] - lptr[l]), 1.0f));
  if (l < NV) {
    int d = (lptr[l + 1] - lptr[l]) + (lptr[l + NV + 1] - lptr[l + NV]);
    vdw[l] = 4.0f * rsqrtf(fmaxf((float)d, 1.0f));
  }
}

__global__ __launch_bounds__(256) void k_init_v(float* __restrict__ variables, bf16* __restrict__ ugA) {
  int i = blockIdx.x * 256 + threadIdx.x;
  variables[i] = 1.0f;
  ugA[(size_t)(i >> 7) * 512 + 128 + (i & 127)] = 0x3F80;
}
__global__ __launch_bounds__(256) void k_init_c(bf16* __restrict__ cmA) {
  int i = blockIdx.x * 256 + threadIdx.x;
  cmA[(size_t)(i >> 7) * 256 + (i & 127)] = 0x3F80;
}

__global__ __launch_bounds__(256) void k_wt(const float* __restrict__ w, bf16* __restrict__ wt,
                                            int K, int N, int Kpad) {
  int idx = blockIdx.x * 256 + threadIdx.x;
  int n = idx / Kpad, k = idx % Kpad;
  if (n >= N) return;
  wt[idx] = (k < K) ? f2b(w[(size_t)k * N + n]) : (bf16)0;
}

// ---------------- MFMA GEMM body: 128x128 tile, 4 waves, BK=64, 2-phase dbuf ----------------
// AL: AL_STD (all K-tiles from A0), AL_NOISE (tiles 0,1 from A0; tile 2 = noise f32 cols 0-3 pad 0),
//     AL_CM (tiles 0,1: A0; tiles 2,3: A1 cols k0-128; tiles 4,5: A0 cols k0-128; lda=256).
// OUT: 0=f32, 1=bf16 (ldOut), 2=dual bf16 (o0 ld 256, o1 ld 128, split col 128),
//      3=softplus pair f16, 4=fused logits head (o0=out, o1=w1, noise[0]=b1, ldOut=t).
// STAT: accumulate pair_norm colsum/sumsq of the written tile into g.stats (OUT==0 or OUT==2 col>=128 half).

struct GP {
  const bf16* A0; const bf16* A1; int lda;
  const float* noise; const bf16* WT; const float* Bv;
  void* o0; void* o1; int ldOut;
  float* stats;
};

enum { AL_STD = 0, AL_NOISE = 1, AL_CM = 2 };

template <int KDIM, int AL, bool RELU, int OUT, bool STAT = false>
__device__ __forceinline__ void gemm_body(const GP g, int bx, char* smem) {
  constexpr int NT = KDIM / 64;
  const int tid = threadIdx.x;
  const int m0 = bx * 128;
  const int n0 = blockIdx.y * 128;
  const int lane = tid & 63;
  const int w = tid >> 6;
  const int wr = w >> 1, wc = w & 1;
  const int rl = (tid >> 3) & 7;
  const int cc = tid & 7;
  const int swzoff = (cc * 16) ^ (rl << 4);

  auto stage = [&](int t, int buf) {
    char* As = smem + buf * 32768;
    char* Bs = As + 16384;
    const int k0 = t * 64;
    if (AL == AL_NOISE && t == 2) {
      const int srow = tid >> 3, schunk = tid & 7;
#pragma unroll
      for (int it = 0; it < 4; ++it) {
        int row = srow + it * 32;
        alignas(16) bf16 tmp[8];
#pragma unroll
        for (int e = 0; e < 8; ++e) {
          int kk = schunk * 8 + e;
          tmp[e] = (kk < 4) ? f2b(g.noise[(size_t)(m0 + row) * 4 + kk]) : (bf16)0;
        }
        *reinterpret_cast<uint4*>(&As[row * 128 + ((schunk * 16) ^ ((row & 7) << 4))]) =
            *reinterpret_cast<uint4*>(tmp);
        int row0 = it * 32 + w * 8;
        gload16((const char*)(g.WT + (size_t)(n0 + row0 + rl) * KDIM + k0) + swzoff, Bs + row0 * 128);
      }
    } else {
      const bf16* Ap = g.A0;
      int co_ = k0;
      if (AL == AL_CM) {
        if (t >= 2 && t < 4) Ap = g.A1;
        if (t >= 2) co_ = k0 - 128;
      }
#pragma unroll
      for (int it = 0; it < 4; ++it) {
        int row0 = it * 32 + w * 8;
        int row = row0 + rl;
        gload16((const char*)(Ap + (size_t)(m0 + row) * g.lda + co_) + swzoff, As + row0 * 128);
        gload16((const char*)(g.WT + (size_t)(n0 + row) * KDIM + k0) + swzoff, Bs + row0 * 128);
      }
    }
  };

  f4 acc[4][4] = {};
  stage(0, 0);
#pragma unroll
  for (int t = 0; t < NT; ++t) {
    const int buf = t & 1;
    __builtin_amdgcn_sched_barrier(0);
    if (t + 1 < NT) {
      stage(t + 1, buf ^ 1);
      if (AL == AL_NOISE && t + 1 == 2) {
        asm volatile("s_waitcnt vmcnt(4) lgkmcnt(0)" ::: "memory");
      } else {
        asm volatile("s_waitcnt vmcnt(8) lgkmcnt(0)" ::: "memory");
      }
    } else {
      asm volatile("s_waitcnt vmcnt(0) lgkmcnt(0)" ::: "memory");
    }
    __builtin_amdgcn_s_barrier();
    __builtin_amdgcn_sched_barrier(0);
    const char* As = smem + buf * 32768;
    const char* Bs = As + 16384;
#pragma unroll
    for (int kk = 0; kk < 2; ++kk) {
      bf8 a[4], b[4];
#pragma unroll
      for (int i = 0; i < 4; ++i) {
        int r = wr * 64 + i * 16 + (lane & 15);
        int cby = (kk * 64 + ((lane >> 4) * 16)) ^ ((r & 7) << 4);
        a[i] = *reinterpret_cast<const bf8*>(&As[r * 128 + cby]);
        int c = wc * 64 + i * 16 + (lane & 15);
        int cby2 = (kk * 64 + ((lane >> 4) * 16)) ^ ((c & 7) << 4);
        b[i] = *reinterpret_cast<const bf8*>(&Bs[c * 128 + cby2]);
      }
#pragma unroll
      for (int i = 0; i < 4; ++i)
#pragma unroll
        for (int j = 0; j < 4; ++j)
          acc[i][j] = __builtin_amdgcn_mfma_f32_16x16x32_bf16(a[i], b[j], acc[i][j], 0, 0, 0);
    }
    __builtin_amdgcn_sched_barrier(0);
    __builtin_amdgcn_s_barrier();
  }
  const int colloc = wc * 64 + (lane & 15);
  const int rowbase = m0 + wr * 64 + ((lane >> 4) << 2);

  if constexpr (OUT == 4) {
    const float* w1 = (const float*)g.o1;
    float* outp = (float*)g.o0;
    const int t = g.ldOut;
    float part[4][4];
#pragma unroll
    for (int i = 0; i < 4; ++i)
#pragma unroll
      for (int p = 0; p < 4; ++p) part[i][p] = 0.0f;
#pragma unroll
    for (int j = 0; j < 4; ++j) {
      int c = colloc + j * 16;
      float bias = g.Bv[c];
      float w1c = w1[c];
#pragma unroll
      for (int i = 0; i < 4; ++i)
#pragma unroll
        for (int p = 0; p < 4; ++p)
          part[i][p] += fmaxf(acc[i][j][p] + bias, 0.0f) * w1c;
    }
#pragma unroll
    for (int m = 1; m < 16; m <<= 1)
#pragma unroll
      for (int i = 0; i < 4; ++i)
#pragma unroll
        for (int p = 0; p < 4; ++p)
          part[i][p] += __shfl_xor(part[i][p], m, 64);
    float* red = (float*)smem;
    if ((lane & 15) == 0) {
#pragma unroll
      for (int i = 0; i < 4; ++i)
#pragma unroll
        for (int p = 0; p < 4; ++p)
          red[wc * 128 + wr * 64 + i * 16 + ((lane >> 4) << 2) + p] = part[i][p];
    }
    __syncthreads();
    if (tid < 128) {
      float lg = red[tid] + red[128 + tid] + g.noise[0];
      int row = m0 + tid;
      outp[(size_t)t * NC + row] = fsigm(lg);
      outp[(size_t)4 * NC + (size_t)t * NC + row] = fsoftplus(lg);
    }
    return;
  }

  float colpart[4] = {0.0f, 0.0f, 0.0f, 0.0f};
  float sq = 0.0f;
  const bool statact = STAT && (OUT == 0 || n0 == 128);

#pragma unroll
  for (int j = 0; j < 4; ++j) {
    int c = n0 + colloc + j * 16;
    float bias = g.Bv[c];
#pragma unroll
    for (int i = 0; i < 4; ++i) {
      int rb = rowbase + i * 16;
#pragma unroll
      for (int p = 0; p < 4; ++p) {
        float v = acc[i][j][p] + bias;
        if (RELU) v = fmaxf(v, 0.0f);
        int r = rb + p;
        if constexpr (STAT) {
          if (statact) { colpart[j] += v; sq += v * v; }
        }
        if constexpr (OUT == 0) {
          ((float*)g.o0)[(size_t)r * g.ldOut + c] = v;
        } else if constexpr (OUT == 1) {
          ((bf16*)g.o0)[(size_t)r * g.ldOut + c] = f2b(v);
        } else if constexpr (OUT == 2) {
          if (c < 128) ((bf16*)g.o0)[(size_t)r * 256 + c] = f2b(v);
          else ((bf16*)g.o1)[(size_t)r * 128 + (c - 128)] = f2b(v);
        } else {  // OUT==3
          float tq = LN2 * flog2(1.0f + fexp2(-fabsf(v) * LOG2E));
          ((f16*)g.o0)[(size_t)r * 128 + c] = (f16)(fmaxf(v, 0.0f) + tq);
          ((f16*)g.o1)[(size_t)r * 128 + c] = (f16)(fmaxf(-v, 0.0f) + tq);
        }
      }
    }
  }

  if constexpr (STAT) {
    if (statact) {
      // reduce rows within wave: lanes differing in bits 4,5 cover the 4 row-groups
#pragma unroll
      for (int m = 16; m <= 32; m <<= 1)
#pragma unroll
        for (int j = 0; j < 4; ++j)
          colpart[j] += __shfl_xor(colpart[j], m, 64);
#pragma unroll
      for (int m = 1; m <= 32; m <<= 1) sq += __shfl_xor(sq, m, 64);
      float* csl = (float*)smem;  // [129]
      if (tid <= 128) csl[tid] = 0.0f;
      __syncthreads();
      if ((lane & 48) == 0) {  // lane < 16 within wave
#pragma unroll
        for (int j = 0; j < 4; ++j)
          atomicAdd(&csl[wc * 64 + (lane & 15) + j * 16], colpart[j]);
      }
      if (lane == 0) atomicAdd(&csl[128], sq);
      __syncthreads();
      if (tid < 128) atomicAdd(&g.stats[tid], csl[tid]);
      else if (tid == 128) atomicAdd(&g.stats[128], csl[128]);
    }
  }
}

template <int KDIM, int AL, bool RELU, int OUT, bool STAT = false>
__global__ __launch_bounds__(256) void mgemm_s(GP g) {
  __shared__ __align__(16) char smem[65536];
  gemm_body<KDIM, AL, RELU, OUT, STAT>(g, blockIdx.x, smem);
}

template <int KDIM, int AL, bool RELU, int OUTA, int OUTB>
__global__ __launch_bounds__(256) void mgemm_d(GP ga, GP gb, int nA) {
  __shared__ __align__(16) char smem[65536];
  if ((int)blockIdx.x < nA) gemm_body<KDIM, AL, RELU, OUTA>(ga, blockIdx.x, smem);
  else gemm_body<KDIM, AL, RELU, OUTB>(gb, blockIdx.x - nA, smem);
}

// ---------------- graph / elementwise kernels ----------------

// per clause-pair in lockstep (8 loads in flight): csum over precomputed softplus;
// reads cq from gbuf[c][128+q]; writes loss4 -> gbuf[c][q], cg -> cmA[c][128+q].
__global__ __launch_bounds__(256) void k_loss(const int* __restrict__ edge_lit, const int* __restrict__ cptr,
                                              const f16* __restrict__ sp, bf16* __restrict__ gbuf,
                                              bf16* __restrict__ cmA) {
  const int g = threadIdx.x >> 7;
  const int q = threadIdx.x & 127;
  const int c0 = blockIdx.x * 16 + g * 8;
#pragma unroll
  for (int ci = 0; ci < 4; ++ci) {
    int ca = c0 + ci * 2;
    int e0a = cptr[ca], e1a = cptr[ca + 1], e1b = cptr[ca + 2];
    int e0b = e1a;
    float csa = 0.0f, csb = 0.0f;
    int na = e1a - e0a, nb = e1b - e0b;
    int nm = na > nb ? na : nb;
    for (int b = 0; b < nm; b += 4) {
#pragma unroll
      for (int k = 0; k < 4; ++k) {
        int ea = e0a + b + k;
        bool oka = ea < e1a;
        int la = oka ? edge_lit[ea] : 0;
        csa += oka ? (float)sp[(size_t)la * 128 + q] : 0.0f;
        int eb = e0b + b + k;
        bool okb = eb < e1b;
        int lb = okb ? edge_lit[eb] : 0;
        csb += okb ? (float)sp[(size_t)lb * 128 + q] : 0.0f;
      }
    }
    float s = fsigm(b2f(gbuf[(size_t)ca * 256 + 128 + q]));
    float L = fexp2(-csa * LOG2E) * s;
    gbuf[(size_t)ca * 256 + q] = f2b(4.0f * L);
    cmA[(size_t)ca * 256 + 128 + q] = f2b(L * (1.0f - s) * INV_CQM);
    int cb = ca + 1;
    float s2 = fsigm(b2f(gbuf[(size_t)cb * 256 + 128 + q]));
    float L2 = fexp2(-csb * LOG2E) * s2;
    gbuf[(size_t)cb * 256 + q] = f2b(4.0f * L2);
    cmA[(size_t)cb * 256 + 128 + q] = f2b(L2 * (1.0f - s2) * INV_CQM);
  }
}

// per variable: gathers from interleaved gbuf rows + vgrad. Unroll x8 -> 16 loads in flight.
__global__ __launch_bounds__(256) void k_gatherv(const int* __restrict__ lptr, const int* __restrict__ lclause,
                                                 const bf16* __restrict__ gbuf, const f16* __restrict__ spn,
                                                 const float* __restrict__ dw, const float* __restrict__ vdw,
                                                 bf16* __restrict__ ugA) {
  int v = blockIdx.x;
  int half = threadIdx.x >> 7, q = threadIdx.x & 127;
  int l = v + half * NV;
  int j0 = lptr[l], j1 = lptr[l + 1];
  float sg = 0.0f, sv = 0.0f;
  for (int j = j0; j < j1; j += 8) {
#pragma unroll
    for (int k = 0; k < 8; ++k) {
      int jj = j + k;
      bool ok = jj < j1;
      int c = ok ? lclause[jj] : 0;
      float a = ok ? b2f(gbuf[(size_t)c * 256 + q]) : 0.0f;
      float b = ok ? b2f(gbuf[(size_t)c * 256 + 128 + q]) : 0.0f;
      sg += a;
      sv += b;
    }
  }
  __shared__ float sgl[2][128];
  sgl[half][q] = sg;
  ugA[(size_t)v * 512 + 256 + half * 128 + q] = f2b(sv * dw[l]);
  __syncthreads();
  if (half == 0) {
    float s = fexp2(-LOG2E * (float)spn[(size_t)v * 128 + q]);
    float g = ((1.0f - s) * sgl[1][q] - s * sgl[0][q]) * (INV_CQM * 0.25f) * vdw[v];
    ugA[(size_t)v * 512 + q] = f2b(g);
  }
}

// reads raw colsum/sumsq, writes mean + scale to outp, zeroes raw for next use.
__global__ __launch_bounds__(128) void k_pn_final(float* __restrict__ raw, float* __restrict__ outp, float R) {
  __shared__ float s[128];
  int q = threadIdx.x;
  float m = raw[q] / R;
  s[q] = m * m;
  __syncthreads();
  for (int off = 64; off; off >>= 1) {
    if (q < off) s[q] += s[q + off];
    __syncthreads();
  }
  if (q == 0) {
    float var = (raw[128] - R * s[0]) / (R * 128.0f);
    outp[128] = rsqrtf(fmaxf(var, 0.0f) + 1e-6f) * 0.25f;
    raw[128] = 0.0f;
  }
  outp[q] = m;
  raw[q] = 0.0f;
}

__global__ __launch_bounds__(256) void k_pn_apply_c(const bf16* __restrict__ cd1, const float* __restrict__ st,
                                                    bf16* __restrict__ cmA) {
  int i = blockIdx.x * 256 + threadIdx.x;
  int c = i >> 7, q = i & 127;
  float x = b2f(cd1[i]);
  float old = b2f(cmA[(size_t)c * 256 + q]);
  cmA[(size_t)c * 256 + q] = f2b((x - st[q]) * st[128] + 0.1f * old);
}

__global__ __launch_bounds__(256) void k_pn_apply_v(const float* __restrict__ uout, const float* __restrict__ st,
                                                    float* __restrict__ variables, bf16* __restrict__ ugA) {
  int i = blockIdx.x * 256 + threadIdx.x;
  int v = i >> 7, q = i & 127;
  float nv = (uout[i] - st[q]) * st[128] + 0.1f * variables[i];
  variables[i] = nv;
  ugA[(size_t)v * 512 + 128 + q] = f2b(nv);
}

// ---------------- host ----------------

extern "C" void kernel_launch(void* const* d_in, const int* in_sizes, int n_in,
                              void* d_out, int out_size, void* d_ws, size_t ws_size,
                              hipStream_t stream) {
  const int* edge_lit = (const int*)d_in[0];
  const int* edge_clause = (const int*)d_in[1];
  const float* noise_v = (const float*)d_in[2];
  const float* noise_c = (const float*)d_in[3];
  const float* vq_w0 = (const float*)d_in[4];  const float* vq_b0 = (const float*)d_in[5];
  const float* vq_w1 = (const float*)d_in[6];  const float* vq_b1 = (const float*)d_in[7];
  const float* cq_w0 = (const float*)d_in[8];  const float* cq_b0 = (const float*)d_in[9];
  const float* cq_w1 = (const float*)d_in[10]; const float* cq_b1 = (const float*)d_in[11];
  const float* cm_w0 = (const float*)d_in[12]; const float* cm_b0 = (const float*)d_in[13];
  const float* cm_w1 = (const float*)d_in[14]; const float* cm_b1 = (const float*)d_in[15];
  const float* ug_w0 = (const float*)d_in[16]; const float* ug_b0 = (const float*)d_in[17];
  const float* ug_w1 = (const float*)d_in[18]; const float* ug_b1 = (const float*)d_in[19];
  const float* ug_w2 = (const float*)d_in[20]; const float* ug_b2 = (const float*)d_in[21];
  const float* co_w0 = (const float*)d_in[22]; const float* co_b0 = (const float*)d_in[23];
  const float* co_w1 = (const float*)d_in[24]; const float* co_b1 = (const float*)d_in[25];
  float* out = (float*)d_out;

  char* base = (char*)d_ws;
  size_t off = 0;
  auto A = [&](size_t n) -> char* {
    char* p = base + off;
    off = (off + n + 255) & ~(size_t)255;
    return p;
  };
  float* variables = (float*)A((size_t)NV * 128 * 4);
  bf16* cmA        = (bf16*)A((size_t)NC * 256 * 2);    // [clauses_h | cg]
  bf16* gbuf       = (bf16*)A((size_t)NC * 256 * 2);    // [loss4 | cq->cd0] interleaved
  bf16* ugA        = (bf16*)A((size_t)NV * 512 * 2);    // [vgrad | vars_h | vl_lo*dw | vl_hi*dw]
  char* R_h        = A((size_t)NC * 128 * 2);           // hc | cd1 | uh1+uh2
  char* R_big      = A((size_t)CMCHUNK * 256 * 2 + (size_t)2 * NV * 128 * 2);  // hv/cmh/uout | sp
  bf16* wtb        = (bf16*)A(983424);
  int* cptr = (int*)A((size_t)(NC + 1) * 4);
  int* lptr = (int*)A((size_t)(2 * NV + 1) * 4);
  int* lcur = (int*)A((size_t)2 * NV * 4);
  int* lclause = (int*)A((size_t)NE * 4);
  float* dw  = (float*)A((size_t)2 * NV * 4);
  float* vdw = (float*)A((size_t)NV * 4);
  float* stats = (float*)A(2048);  // raw [0..128], out at +256 floats
  if (off > ws_size) {
    hipMemsetAsync(d_out, 0xFF, (size_t)out_size * 4, stream);
    return;
  }
  float* statsOut = stats + 256;

  bf16* hc  = (bf16*)R_h;                          // NC x 128
  bf16* cd1 = (bf16*)R_h;
  bf16* uh1 = (bf16*)R_h;
  bf16* uh2 = (bf16*)(R_h + (size_t)NV * 256 * 2);
  bf16* hv  = (bf16*)R_big;                        // NV x 128 (dead before cmh)
  bf16* cmh = (bf16*)R_big;                        // CMCHUNK x 256
  float* uout = (float*)R_big;                     // NV x 128 f32 (after cmh dead)
  f16* spp  = (f16*)(R_big + (size_t)CMCHUNK * 256 * 2);  // 2NV x 128 f16
  f16* spn  = spp + (size_t)NV * 128;

  size_t wo = 0;
  auto WTa = [&](int n, int kp) { bf16* p = wtb + wo; wo += (size_t)n * kp; return p; };
  bf16* wt_vq0 = WTa(128, 192); bf16* wt_vq1 = WTa(128, 128);
  bf16* wt_cq0 = WTa(128, 192); bf16* wt_cq1 = WTa(128, 128);
  bf16* wt_cm0 = WTa(256, 384); bf16* wt_cm1 = WTa(256, 256);
  bf16* wt_ug0 = WTa(256, 512); bf16* wt_ug1 = WTa(256, 256);
  bf16* wt_ug2 = WTa(128, 256); bf16* wt_co0 = WTa(128, 128);

  hipMemsetAsync(lcur, 0, (size_t)2 * NV * 4, stream);
  hipMemsetAsync(stats, 0, 1024, stream);
  k_cptr<<<(NC + 256) / 256, 256, 0, stream>>>(edge_clause, cptr);
  k_litcnt<<<NE / 256, 256, 0, stream>>>(edge_lit, lcur);
  k_scan<<<1, 1024, 0, stream>>>(lcur, lptr);
  k_fillsort<<<NE / 256, 256, 0, stream>>>(edge_lit, edge_clause, lcur, lclause);
  k_degree<<<(2 * NV + 255) / 256, 256, 0, stream>>>(lptr, dw, vdw);
  k_init_v<<<NV * 128 / 256, 256, 0, stream>>>(variables, ugA);
  k_init_c<<<NC * 128 / 256, 256, 0, stream>>>(cmA);
  k_wt<<<128 * 192 / 256, 256, 0, stream>>>(vq_w0, wt_vq0, 132, 128, 192);
  k_wt<<<128 * 128 / 256, 256, 0, stream>>>(vq_w1, wt_vq1, 128, 128, 128);
  k_wt<<<128 * 192 / 256, 256, 0, stream>>>(cq_w0, wt_cq0, 132, 128, 192);
  k_wt<<<128 * 128 / 256, 256, 0, stream>>>(cq_w1, wt_cq1, 128, 128, 128);
  k_wt<<<256 * 384 / 256, 256, 0, stream>>>(cm_w0, wt_cm0, 384, 256, 384);
  k_wt<<<256 * 256 / 256, 256, 0, stream>>>(cm_w1, wt_cm1, 256, 256, 256);
  k_wt<<<256 * 512 / 256, 256, 0, stream>>>(ug_w0, wt_ug0, 512, 256, 512);
  k_wt<<<256 * 256 / 256, 256, 0, stream>>>(ug_w1, wt_ug1, 256, 256, 256);
  k_wt<<<128 * 256 / 256, 256, 0, stream>>>(ug_w2, wt_ug2, 256, 128, 256);
  k_wt<<<128 * 128 / 256, 256, 0, stream>>>(co_w0, wt_co0, 128, 128, 128);

  for (int t = 0; t < 4; ++t) {
    const float* nvp = noise_v + (size_t)t * NV * 4;
    const float* ncp = noise_c + (size_t)t * NC * 4;
    // merged layer-0: vq0 (192 blocks) + cq0 (768 blocks)
    {
      GP pa{ugA + 128, nullptr, 512, nvp, wt_vq0, vq_b0, hv, nullptr, 128};
      GP pb{cmA, nullptr, 256, ncp, wt_cq0, cq_b0, hc, nullptr, 128};
      mgemm_d<192, AL_NOISE, true, 1, 1><<<dim3(960, 1), 256, 0, stream>>>(pa, pb, 192);
    }
    // merged layer-1: vq1 -> softplus pair f16 + cq1 -> gbuf cq slot
    {
      GP pa{hv, nullptr, 128, nullptr, wt_vq1, vq_b1, spp, spn, 128};
      GP pb{hc, nullptr, 128, nullptr, wt_cq1, cq_b1, gbuf + 128, nullptr, 256};
      mgemm_d<128, AL_STD, false, 3, 1><<<dim3(960, 1), 256, 0, stream>>>(pa, pb, 192);
    }
    k_loss<<<NC / 16, 256, 0, stream>>>(edge_lit, cptr, spp, gbuf, cmA);
    // clause_data MLP — 2 chunks; cm1 fuses cd1 pair_norm stats
    for (int ch = 0; ch < NC / CMCHUNK; ++ch) {
      size_t ro = (size_t)ch * CMCHUNK;
      GP p0{cmA + ro * 256, gbuf + ro * 256, 256, nullptr, wt_cm0, cm_b0, cmh, nullptr, 256};
      mgemm_s<384, AL_CM, true, 1><<<dim3(CMCHUNK / 128, 2), 256, 0, stream>>>(p0);
      GP p1{cmh, nullptr, 256, nullptr, wt_cm1, cm_b1, gbuf + ro * 256 + 128, cd1 + ro * 128, 0, stats};
      mgemm_s<256, AL_STD, false, 2, true><<<dim3(CMCHUNK / 128, 2), 256, 0, stream>>>(p1);
    }
    // merged gathers + vgrad
    k_gatherv<<<NV, 256, 0, stream>>>(lptr, lclause, gbuf, spn, dw, vdw, ugA);
    // clauses pair_norm finalize + apply
    k_pn_final<<<1, 128, 0, stream>>>(stats, statsOut, (float)NC);
    k_pn_apply_c<<<NC * 128 / 256, 256, 0, stream>>>(cd1, statsOut, cmA);
    // fused logits head
    {
      GP p{cmA, nullptr, 256, co_b1, wt_co0, co_b0, out, (void*)co_w1, t};
      mgemm_s<128, AL_STD, false, 4><<<dim3(NC / 128, 1), 256, 0, stream>>>(p);
    }
    // variables = pair_norm(mlp3(ugA))*0.25 + 0.1*variables; ug2 fuses stats
    {
      GP p{ugA, nullptr, 512, nullptr, wt_ug0, ug_b0, uh1, nullptr, 256};
      mgemm_s<512, AL_STD, true, 1><<<dim3(NV / 128, 2), 256, 0, stream>>>(p);
    }
    {
      GP p{uh1, nullptr, 256, nullptr, wt_ug1, ug_b1, uh2, nullptr, 256};
      mgemm_s<256, AL_STD, true, 1><<<dim3(NV / 128, 2), 256, 0, stream>>>(p);
    }
    {
      GP p{uh2, nullptr, 256, nullptr, wt_ug2, ug_b2, uout, nullptr, 128, stats};
      mgemm_s<256, AL_STD, false, 0, true><<<dim3(NV / 128, 1), 256, 0, stream>>>(p);
    }
    k_pn_final<<<1, 128, 0, stream>>>(stats, statsOut, (float)NV);
    k_pn_apply_v<<<NV * 128 / 256, 256, 0, stream>>>(uout, statsOut, variables, ugA);
  }
}